// Round 7
// baseline (3213.242 us; speedup 1.0000x reference)
//
#include <hip/hip_runtime.h>

// ---------------------------------------------------------------------------
// GGNN-obj (N=256, C=151, H=512, T=3). Split-f16 (hi+lo) MFMA on the
// recurrent path, f32 hidden master.
// R6->R7: ew1 fused into gate-GEMM epilogue (z / r*h per column range);
// ew2 fused into p5u-GEMM epilogue (tanh + hidden update, full K=512).
// NOTE: SQ_LDS_BANK_CONFLICT = 4/ds_read_b128 is structural (8 phases for
// 1024B wave read) — invariant under swizzle; not a real conflict.
// ---------------------------------------------------------------------------

#define C_     151
#define H_     512
#define NOBJ   256
#define NR     38656      // NOBJ * C_
#define NCH    64         // objects per chunk
#define CH     9664       // NCH * C_
#define CHP    9728       // CH padded to 128-multiple (76 tiles)
#define KPAD   160        // C_ padded to 32-multiple
#define KLDS   168        // LDS row stride for transposed x tiles
#define KA     2560       // A cols in gate GEMM: [av_hi 1024 | av_lo 1024 | h 512]
#define KV     3584       // virtual K: ah*Wh + al*Wh + ah*Wl + h*Wu

typedef _Float16 half8 __attribute__((ext_vector_type(8)));
typedef _Float16 half4 __attribute__((ext_vector_type(4)));
typedef float    f32x4 __attribute__((ext_vector_type(4)));

__device__ __forceinline__ float sigm(float x) { return 1.f / (1.f + expf(-x)); }

__device__ __forceinline__ void gload16(const void* g, void* l) {
    __builtin_amdgcn_global_load_lds(
        (const __attribute__((address_space(1))) void*)g,
        (__attribute__((address_space(3))) void*)l, 16, 0, 0);
}

__device__ __forceinline__ int kqswz(int s) {
    return 8 * (((s & 3) + 8 - ((s >> 2) & 3) - ((s >> 4) & 3)) & 3);
}
__device__ __forceinline__ int fraswz(int lane) {
    const int lb = lane & 15;
    return lb * 32 + 8 * (((lane >> 4) + lb + (lb >> 2)) & 3);
}

__device__ __forceinline__ half8 loadA8(const _Float16* p) { return *(const half8*)p; }
__device__ __forceinline__ half8 loadA8(const float* p) {
    f32x4 a = *(const f32x4*)p;
    f32x4 b = *(const f32x4*)(p + 4);
    half8 o;
    #pragma unroll
    for (int j = 0; j < 4; ++j) { o[j] = (_Float16)a[j]; o[4 + j] = (_Float16)b[j]; }
    return o;
}

// ---------------------------------------------------------------------------
// 128x128-tile GEMM (256 thr): Out[m,n] = sum_k A[m,k]*B[n,k].
// OP: 0 = f32 store, 1 = f16 store,
//     2 = relu(v + bias[col] + bias2[(row/151)*512+col]) -> f16
//     3 = p5u+ew2 fused: t = tanh(v + pre[row*1536+1024+col] + bias[col]);
//         z = pre[row*1536+col]; hid[cbase+row][col] = (1-z)h + z*t  (row<CH)
// ---------------------------------------------------------------------------
template<int OP, typename AT, bool DUPK>
__global__ __launch_bounds__(256, 2)
void gemm_kernel(const AT* __restrict__ A, int lda,
                 const _Float16* __restrict__ B, int ldb,
                 void* __restrict__ Out, int ldo,
                 const float* __restrict__ bias,
                 const float* __restrict__ bias2,
                 int kchunk, int chunkStride,
                 const _Float16* __restrict__ X1,
                 float* __restrict__ hidp, int cbase)
{
    constexpr bool A16 = (sizeof(AT) == 2);
    __shared__ _Float16 sA[128 * 32];
    __shared__ _Float16 sB[128 * 32];
    const int tid  = threadIdx.x;
    const int lane = tid & 63;
    const int w    = tid >> 6;
    const int m0   = blockIdx.x * 128;
    const int n0   = blockIdx.y * 128;
    const int kbase = blockIdx.z * kchunk;

    const int s0 = tid, s1 = tid + 256;
    const AT* Ap0 = A + (size_t)(m0 + (s0 >> 2)) * lda + kqswz(s0);
    const AT* Ap1 = A + (size_t)(m0 + (s1 >> 2)) * lda + kqswz(s1);
    const _Float16* Bp0 = B + (size_t)(n0 + (s0 >> 2)) * ldb + kbase + kqswz(s0);
    const _Float16* Bp1 = B + (size_t)(n0 + (s1 >> 2)) * ldb + kbase + kqswz(s1);
    const int la0 = 8 * s0;
    const int la1 = 8 * s1;
    _Float16* lA0 = &sA[w * 512];
    _Float16* lA1 = &sA[2048 + w * 512];
    _Float16* lB0 = &sB[w * 512];
    _Float16* lB1 = &sB[2048 + w * 512];

    f32x4 acc[4][4];
    #pragma unroll
    for (int i = 0; i < 4; ++i)
        #pragma unroll
        for (int j = 0; j < 4; ++j)
            #pragma unroll
            for (int r = 0; r < 4; ++r) acc[i][j][r] = 0.f;

    const int mrow = (w >> 1) * 64;
    const int ncol = (w & 1) * 64;
    const int fra  = fraswz(lane);

    for (int k0 = 0; k0 < kchunk; k0 += 32) {
        int kA;
        if (DUPK) kA = (k0 < 2048) ? k0 : ((k0 < 3072) ? k0 - 2048 : k0 - 1024);
        else      kA = kbase + k0;
        if constexpr (A16) {
            __syncthreads();
            gload16(Ap0 + kA, lA0);
            gload16(Ap1 + kA, lA1);
            gload16(Bp0 + k0, lB0);
            gload16(Bp1 + k0, lB1);
            __syncthreads();
        } else {
            half8 va0 = loadA8(Ap0 + kA);
            half8 va1 = loadA8(Ap1 + kA);
            half8 vb0 = *(const half8*)(Bp0 + k0);
            half8 vb1 = *(const half8*)(Bp1 + k0);
            __syncthreads();
            *(half8*)&sA[la0] = va0;
            *(half8*)&sA[la1] = va1;
            *(half8*)&sB[la0] = vb0;
            *(half8*)&sB[la1] = vb1;
            __syncthreads();
        }
        half8 af[4], bf[4];
        #pragma unroll
        for (int i = 0; i < 4; ++i)
            af[i] = *(const half8*)&sA[(mrow + i * 16) * 32 + fra];
        #pragma unroll
        for (int i = 0; i < 4; ++i)
            bf[i] = *(const half8*)&sB[(ncol + i * 16) * 32 + fra];
        #pragma unroll
        for (int mi = 0; mi < 4; ++mi)
            #pragma unroll
            for (int ni = 0; ni < 4; ++ni)
                acc[mi][ni] = __builtin_amdgcn_mfma_f32_16x16x32_f16(af[mi], bf[ni], acc[mi][ni], 0, 0, 0);
    }

    const size_t zoff = (size_t)blockIdx.z * (size_t)chunkStride;
    #pragma unroll
    for (int mi = 0; mi < 4; ++mi) {
        #pragma unroll
        for (int ni = 0; ni < 4; ++ni) {
            #pragma unroll
            for (int r = 0; r < 4; ++r) {
                const int row = m0 + mrow + mi * 16 + (lane >> 4) * 4 + r;
                const int col = n0 + ncol + ni * 16 + (lane & 15);
                float v = acc[mi][ni][r];
                const size_t o = zoff + (size_t)row * ldo + col;
                if (OP == 0) {
                    ((float*)Out)[o] = v;
                } else if (OP == 1) {
                    ((_Float16*)Out)[o] = (_Float16)v;
                } else if (OP == 2) {
                    const unsigned n = (unsigned)row / 151u;
                    v += bias[col] + bias2[n * 512u + col];
                    v = v > 0.f ? v : 0.f;
                    ((_Float16*)Out)[o] = (_Float16)v;
                } else {
                    // p5u + ew2 fused
                    if (row < CH) {
                        const size_t pb = (size_t)row * 1536;
                        const float w5 = (float)X1[pb + 1024 + col];
                        const float zv = (float)X1[pb + col];
                        const float t  = tanhf(v + w5 + bias[col]);
                        float* hp = &hidp[(size_t)(cbase + row) * H_ + col];
                        *hp = (1.f - zv) * (*hp) + zv * t;
                    }
                }
            }
        }
    }
}

// ---------------------------------------------------------------------------
// 128(M)x256(N)-tile GEMM, 512 threads = 8 waves of 64x64. f16 A, DMA staging.
// OP: 1 = f16 store
//     3 = gate epilogue: col<512: z=sigm(v+bz[col]); col in [512,1024):
//         rr=sigm(v+br[col-512]); v=rr*h (h from hidp, row<CH); else raw.
//         All stored f16 at Out[row*ldo+col].
// ---------------------------------------------------------------------------
template<int OP, bool DUPK>
__global__ __launch_bounds__(512, 2)
void gemm_wide(const _Float16* __restrict__ A, int lda,
               const _Float16* __restrict__ B, int ldb,
               void* __restrict__ Out, int ldo,
               int kchunk, int chunkStride,
               const float* __restrict__ bz,
               const float* __restrict__ br,
               const float* __restrict__ hidp, int cbase)
{
    __shared__ _Float16 sA[128 * 32];
    __shared__ _Float16 sB[256 * 32];
    const int tid  = threadIdx.x;
    const int lane = tid & 63;
    const int w    = tid >> 6;              // 0..7
    const int m0   = blockIdx.x * 128;
    const int n0   = blockIdx.y * 256;
    const int kbase = blockIdx.z * kchunk;

    const int kq = kqswz(tid);
    const _Float16* Ap = A + (size_t)(m0 + (tid >> 2)) * lda + kq;
    const _Float16* Bp0 = B + (size_t)(n0 + (tid >> 2)) * ldb + kbase + kq;
    const _Float16* Bp1 = B + (size_t)(n0 + 128 + (tid >> 2)) * ldb + kbase + kq;
    _Float16* lA  = &sA[w * 512];
    _Float16* lB0 = &sB[w * 512];
    _Float16* lB1 = &sB[4096 + w * 512];

    f32x4 acc[4][4];
    #pragma unroll
    for (int i = 0; i < 4; ++i)
        #pragma unroll
        for (int j = 0; j < 4; ++j)
            #pragma unroll
            for (int r = 0; r < 4; ++r) acc[i][j][r] = 0.f;

    const int mrow = (w >> 2) * 64;
    const int ncol = (w & 3) * 64;
    const int fra  = fraswz(lane);

    for (int k0 = 0; k0 < kchunk; k0 += 32) {
        int kA;
        if (DUPK) kA = (k0 < 2048) ? k0 : ((k0 < 3072) ? k0 - 2048 : k0 - 1024);
        else      kA = kbase + k0;
        __syncthreads();
        gload16(Ap + kA, lA);
        gload16(Bp0 + k0, lB0);
        gload16(Bp1 + k0, lB1);
        __syncthreads();
        half8 af[4], bf[4];
        #pragma unroll
        for (int i = 0; i < 4; ++i)
            af[i] = *(const half8*)&sA[(mrow + i * 16) * 32 + fra];
        #pragma unroll
        for (int i = 0; i < 4; ++i)
            bf[i] = *(const half8*)&sB[(ncol + i * 16) * 32 + fra];
        #pragma unroll
        for (int mi = 0; mi < 4; ++mi)
            #pragma unroll
            for (int ni = 0; ni < 4; ++ni)
                acc[mi][ni] = __builtin_amdgcn_mfma_f32_16x16x32_f16(af[mi], bf[ni], acc[mi][ni], 0, 0, 0);
    }

    const size_t zoff = (size_t)blockIdx.z * (size_t)chunkStride;
    #pragma unroll
    for (int mi = 0; mi < 4; ++mi) {
        #pragma unroll
        for (int ni = 0; ni < 4; ++ni) {
            #pragma unroll
            for (int r = 0; r < 4; ++r) {
                const int row = m0 + mrow + mi * 16 + (lane >> 4) * 4 + r;
                const int col = n0 + ncol + ni * 16 + (lane & 15);
                float v = acc[mi][ni][r];
                const size_t o = zoff + (size_t)row * ldo + col;
                if (OP == 3) {
                    if (col < 512) {
                        v = sigm(v + bz[col]);
                    } else if (col < 1024) {
                        const float rr = sigm(v + br[col - 512]);
                        const float h = (row < CH)
                            ? hidp[(size_t)(cbase + row) * H_ + (col - 512)] : 0.f;
                        v = rr * h;
                    }
                    ((_Float16*)Out)[o] = (_Float16)v;
                } else {
                    ((_Float16*)Out)[o] = (_Float16)v;
                }
            }
        }
    }
}

// ---------------------------------------------------------------------------
// Mix kernel (one 64-object chunk), split precision, xcast fused.
// ---------------------------------------------------------------------------
__global__ __launch_bounds__(256, 2)
void mix_kernel(const float* __restrict__ hid, const float* __restrict__ S,
                const _Float16* __restrict__ MTh, const _Float16* __restrict__ MTl,
                const _Float16* __restrict__ Mrh, const _Float16* __restrict__ Mrl,
                _Float16* __restrict__ AVH, int cbase)
{
    __shared__ _Float16 sxh[64 * KLDS];
    __shared__ _Float16 sxl[64 * KLDS];
    const int n  = blockIdx.x;
    const int h0 = blockIdx.y * 64;
    const int tid = threadIdx.x;

    #pragma unroll
    for (int i = 0; i < 5; ++i) {
        const int s  = tid + 256 * i;          // 0..1279
        const int c  = s >> 3;                 // 0..159
        const int hg = s & 7;
        half8 oh, ol;
        if (c < C_) {
            const float* hp = &hid[(size_t)(cbase + n * C_ + c) * H_ + h0 + hg * 8];
            const float* sp = &S[c * H_ + h0 + hg * 8];
            half8 hh;
            #pragma unroll
            for (int j = 0; j < 8; ++j) {
                const float hv = hp[j];
                const float x = sp[j] - hv;
                const _Float16 hi = (_Float16)x;
                oh[j] = hi;
                ol[j] = (_Float16)(x - (float)hi);
                hh[j] = (_Float16)hv;
            }
            *(half8*)&AVH[(size_t)(n * C_ + c) * KA + 2048 + h0 + hg * 8] = hh;
        } else {
            #pragma unroll
            for (int j = 0; j < 8; ++j) { oh[j] = (_Float16)0.f; ol[j] = (_Float16)0.f; }
        }
        #pragma unroll
        for (int j = 0; j < 8; ++j) {
            sxh[(hg * 8 + j) * KLDS + c] = oh[j];
            sxl[(hg * 8 + j) * KLDS + c] = ol[j];
        }
    }
    __syncthreads();

    const int lane = tid & 63;
    const int w    = tid >> 6;
    const _Float16* Mhi = (w >> 1) ? Mrh : MTh;
    const _Float16* Mlo = (w >> 1) ? Mrl : MTl;
    const int hb = (w & 1) * 32;

    f32x4 acc[10][2];
    #pragma unroll
    for (int i = 0; i < 10; ++i)
        #pragma unroll
        for (int j = 0; j < 2; ++j)
            #pragma unroll
            for (int r = 0; r < 4; ++r) acc[i][j][r] = 0.f;

    #pragma unroll
    for (int pass = 0; pass < 3; ++pass) {
        const _Float16* Ma = (pass == 2) ? Mlo : Mhi;
        const _Float16* X  = (pass == 1) ? sxl : sxh;
        #pragma unroll
        for (int kk = 0; kk < 5; ++kk) {
            const int k0 = kk * 32;
            half8 bf[2];
            #pragma unroll
            for (int ht = 0; ht < 2; ++ht)
                bf[ht] = *(const half8*)&X[(hb + ht * 16 + (lane & 15)) * KLDS + k0 + 8 * (lane >> 4)];
            #pragma unroll
            for (int dt = 0; dt < 10; ++dt) {
                half8 af = *(const half8*)&Ma[(dt * 16 + (lane & 15)) * KPAD + k0 + 8 * (lane >> 4)];
                acc[dt][0] = __builtin_amdgcn_mfma_f32_16x16x32_f16(af, bf[0], acc[dt][0], 0, 0, 0);
                acc[dt][1] = __builtin_amdgcn_mfma_f32_16x16x32_f16(af, bf[1], acc[dt][1], 0, 0, 0);
            }
        }
    }

    const int mixoff = (w >> 1) * 512;
    #pragma unroll
    for (int dt = 0; dt < 10; ++dt) {
        #pragma unroll
        for (int ht = 0; ht < 2; ++ht) {
            #pragma unroll
            for (int r = 0; r < 4; ++r) {
                const int d = dt * 16 + (lane >> 4) * 4 + r;
                if (d < C_) {
                    const int h = h0 + hb + ht * 16 + (lane & 15);
                    const float v = acc[dt][ht][r];
                    const _Float16 hi = (_Float16)v;
                    const _Float16 lo = (_Float16)(v - (float)hi);
                    _Float16* rowp = AVH + (size_t)(n * C_ + d) * KA + mixoff + h;
                    rowp[0]    = hi;
                    rowp[1024] = lo;
                }
            }
        }
    }
}

// --------------------------- small kernels ---------------------------------

__global__ void k_sreduce(const float* __restrict__ hid, float* __restrict__ Stmp)
{
    const int c  = blockIdx.x;      // 151
    const int g  = blockIdx.y;      // 8
    const int hw = threadIdx.x;     // 64
    const float* p = hid + (size_t)c * H_ + hw * 8;
    float s[8];
    #pragma unroll
    for (int j = 0; j < 8; ++j) s[j] = 0.f;
    const size_t stride = (size_t)C_ * H_;
    for (int n = g * 32; n < g * 32 + 32; ++n) {
        f32x4 a = *(const f32x4*)(p + (size_t)n * stride);
        f32x4 b = *(const f32x4*)(p + (size_t)n * stride + 4);
        #pragma unroll
        for (int j = 0; j < 4; ++j) { s[j] += a[j]; s[4 + j] += b[j]; }
    }
    float* o = Stmp + (size_t)g * (C_ * H_) + c * H_ + hw * 8;
    *(f32x4*)o       = f32x4{s[0], s[1], s[2], s[3]};
    *(f32x4*)(o + 4) = f32x4{s[4], s[5], s[6], s[7]};
}

__global__ void k_sfold(const float* __restrict__ Stmp, float* __restrict__ S)
{
    const int idx = blockIdx.x * 256 + threadIdx.x;   // 77312
    float s = 0.f;
    #pragma unroll
    for (int g = 0; g < 8; ++g) s += Stmp[(size_t)g * (C_ * H_) + idx];
    S[idx] = s;
}

// --------------------------- prep kernels ----------------------------------

__global__ void prep_wbig(const float* w3w, const float* w3u,
                          const float* w4w, const float* w4u,
                          const float* w5w, const float* w5u,
                          _Float16* __restrict__ Wbig)
{
    const int idx = blockIdx.x * 256 + threadIdx.x;   // 1536*3584
    const int op = idx / KV;
    const int j = idx - op * KV;
    const int g = op >> 9, o = op & 511;
    const float* ww = (g == 0) ? w3w : (g == 1) ? w4w : w5w;
    const float* wu = (g == 0) ? w3u : (g == 1) ? w4u : w5u;
    _Float16 out;
    if (j < 1024) {
        out = (_Float16)ww[o * 1024 + j];
    } else if (j < 2048) {
        out = (_Float16)ww[o * 1024 + (j - 1024)];
    } else if (j < 3072) {
        const float v = ww[o * 1024 + (j - 2048)];
        const _Float16 hi = (_Float16)v;
        out = (_Float16)(v - (float)hi);
    } else {
        out = (g < 2) ? (_Float16)wu[o * 512 + (j - 3072)] : (_Float16)0.f;
    }
    Wbig[idx] = out;
}

__global__ void prep_m(const float* __restrict__ matrix,
                       _Float16* __restrict__ MTh, _Float16* __restrict__ MTl,
                       _Float16* __restrict__ Mrh, _Float16* __restrict__ Mrl)
{
    const int idx = blockIdx.x * 256 + threadIdx.x;   // KPAD*KPAD
    const int d = idx / KPAD, c = idx - d * KPAD;
    float vT = 0.f, vR = 0.f;
    if (d < C_ && c < C_) { vT = matrix[c * C_ + d]; vR = matrix[d * C_ + c]; }
    const _Float16 th = (_Float16)vT;
    const _Float16 rh = (_Float16)vR;
    MTh[idx] = th; MTl[idx] = (_Float16)(vT - (float)th);
    Mrh[idx] = rh; Mrl[idx] = (_Float16)(vR - (float)rh);
}

__global__ void prep_wout(const float* __restrict__ wout,
                          _Float16* __restrict__ WL, _Float16* __restrict__ WR)
{
    const int idx = blockIdx.x * 256 + threadIdx.x;   // 512*512
    const int o = idx >> 9, j = idx & 511;
    WL[idx] = (_Float16)wout[o * 1024 + j];
    WR[idx] = (_Float16)wout[o * 1024 + 512 + j];
}

__global__ void prep_wcls(const float* __restrict__ wcls, _Float16* __restrict__ w16)
{
    const int k = blockIdx.x * 256 + threadIdx.x;   // 77312
    const int d = blockIdx.y;                        // 0..255
    _Float16 v = (_Float16)0.f;
    if (d < C_) v = (_Float16)wcls[(size_t)d * (C_ * H_) + k];
    w16[(size_t)d * (C_ * H_) + k] = v;
}

__global__ void k_cast(const float* __restrict__ src, _Float16* __restrict__ dst, int n)
{
    const int i = blockIdx.x * 256 + threadIdx.x;
    if (i < n) dst[i] = (_Float16)src[i];
}

__global__ void prep_bias(const float* b3w, const float* b3u, const float* b4w,
                          const float* b4u, const float* b5w, const float* b5u,
                          float* bz, float* br, float* b5)
{
    const int i = threadIdx.x;   // 512 threads
    bz[i] = b3w[i] + b3u[i];
    br[i] = b4w[i] + b4u[i];
    b5[i] = b5w[i] + b5u[i];
}

__global__ void prep_hid(const float* __restrict__ input, float* __restrict__ hid)
{
    const int idx = blockIdx.x * 256 + threadIdx.x;   // NR*128
    const unsigned row = idx >> 7;
    const int h4 = (idx & 127) << 2;
    const unsigned n = row / 151u;
    f32x4 v = *(const f32x4*)&input[(size_t)n * H_ + h4];
    *(f32x4*)&hid[(size_t)row * H_ + h4] = v;
}

__global__ void k_reduce(const float* __restrict__ partial, const float* __restrict__ bcls,
                         float* __restrict__ out)
{
    const int idx = blockIdx.x * 256 + threadIdx.x;   // NR
    const unsigned n = (unsigned)idx / 151u;
    const unsigned d = (unsigned)idx - n * 151u;
    float s = 0.f;
    for (int z = 0; z < C_; ++z)
        s += partial[(size_t)z * (NOBJ * 256) + n * 256 + d];
    out[idx] = s + bcls[d];
}

// ---------------------------------------------------------------------------

extern "C" void kernel_launch(void* const* d_in, const int* in_sizes, int n_in,
                              void* d_out, int out_size, void* d_ws, size_t ws_size,
                              hipStream_t stream)
{
    const float* input  = (const float*)d_in[0];
    const float* matrix = (const float*)d_in[1];
    const float* w3w = (const float*)d_in[2];
    const float* b3w = (const float*)d_in[3];
    const float* w3u = (const float*)d_in[4];
    const float* b3u = (const float*)d_in[5];
    const float* w4w = (const float*)d_in[6];
    const float* b4w = (const float*)d_in[7];
    const float* w4u = (const float*)d_in[8];
    const float* b4u = (const float*)d_in[9];
    const float* w5w = (const float*)d_in[10];
    const float* b5w = (const float*)d_in[11];
    const float* w5u = (const float*)d_in[12];
    const float* b5u = (const float*)d_in[13];
    const float* wout = (const float*)d_in[14];
    const float* bout = (const float*)d_in[15];
    const float* wcls = (const float*)d_in[16];
    const float* bcls = (const float*)d_in[17];
    float* obj = (float*)d_out;

    char* ws = (char*)d_ws;
    size_t off = 0;
    auto take = [&](size_t bytes) -> char* {
        off = (off + 255) & ~(size_t)255;
        char* p = ws + off;
        off += bytes;
        return p;
    };

    _Float16* Wbig  = (_Float16*)take((size_t)1536 * KV * 2);     // 11.01 MB
    _Float16* MTh   = (_Float16*)take((size_t)KPAD * KPAD * 2);
    _Float16* MTl   = (_Float16*)take((size_t)KPAD * KPAD * 2);
    _Float16* Mrh   = (_Float16*)take((size_t)KPAD * KPAD * 2);
    _Float16* Mrl   = (_Float16*)take((size_t)KPAD * KPAD * 2);
    _Float16* W5u16 = (_Float16*)take((size_t)512 * 512 * 2);
    _Float16* WL16  = (_Float16*)take((size_t)512 * 512 * 2);
    _Float16* WR16  = (_Float16*)take((size_t)512 * 512 * 2);
    _Float16* in16  = (_Float16*)take((size_t)256 * 512 * 2);
    float*    bz    = (float*)take(512 * 4);
    float*    br    = (float*)take(512 * 4);
    float*    b5    = (float*)take(512 * 4);
    float*    Stmp  = (float*)take((size_t)8 * C_ * H_ * 4);      //  2.47 MB
    float*    S32   = (float*)take((size_t)C_ * H_ * 4);
    float*    base  = (float*)take((size_t)256 * 512 * 4);
    float*    hid32 = (float*)take((size_t)NR * H_ * 4);          // 79.17 MB
    _Float16* AVH   = (_Float16*)take((size_t)CHP * KA * 2);      // 49.81 MB
    _Float16* prec  = (_Float16*)take((size_t)CHP * 1536 * 2);    // 29.88 MB
    // time-based aliases:
    _Float16* OUT16 = AVH;               // epilogue out (after loop)
    _Float16* Wcls16 = (_Float16*)hid32; // hid dead after epilogue GEMM
    float* partial = (float*)((char*)hid32 + (size_t)NOBJ * C_ * H_ * 2);

    (void)in_sizes; (void)n_in; (void)out_size; (void)ws_size;

    // ---- prep ----
    prep_wbig<<<dim3((1536 * KV) / 256), 256, 0, stream>>>(w3w, w3u, w4w, w4u, w5w, w5u, Wbig);
    prep_m<<<dim3((KPAD * KPAD) / 256), 256, 0, stream>>>(matrix, MTh, MTl, Mrh, Mrl);
    k_cast<<<dim3((512 * 512) / 256), 256, 0, stream>>>(w5u, W5u16, 512 * 512);
    prep_wout<<<dim3((512 * 512) / 256), 256, 0, stream>>>(wout, WL16, WR16);
    k_cast<<<dim3((256 * 512) / 256), 256, 0, stream>>>(input, in16, 256 * 512);
    prep_bias<<<dim3(1), 512, 0, stream>>>(b3w, b3u, b4w, b4u, b5w, b5u, bz, br, b5);
    prep_hid<<<dim3((NR * 128) / 256), 256, 0, stream>>>(input, hid32);
    gemm_kernel<0, _Float16, false><<<dim3(2, 4, 1), 256, 0, stream>>>(
        in16, 512, WR16, 512, base, 512, nullptr, nullptr, 512, 0, nullptr, nullptr, 0);

    // ---- 3 GGNN steps, 4 object-chunks each ----
    for (int t = 0; t < 3; ++t) {
        k_sreduce<<<dim3(C_, 8), 64, 0, stream>>>(hid32, Stmp);
        k_sfold<<<dim3((C_ * H_) / 256), 256, 0, stream>>>(Stmp, S32);
        for (int cc = 0; cc < 4; ++cc) {
            const int cbase = cc * CH;
            mix_kernel<<<dim3(NCH, 8), 256, 0, stream>>>(
                hid32, S32, MTh, MTl, Mrh, Mrl, AVH, cbase);
            // gate GEMM + ew1 fused epilogue: writes z | r*h | raw w5 into prec
            gemm_wide<3, true><<<dim3(CHP / 128, 1536 / 256, 1), 512, 0, stream>>>(
                AVH, KA, Wbig, KV, prec, 1536, KV, 0, bz, br, hid32, cbase);
            // p5u GEMM + ew2 fused epilogue: updates hid32 in place (full K=512)
            gemm_kernel<3, _Float16, false><<<dim3(CHP / 128, 4, 1), 256, 0, stream>>>(
                prec + 512, 1536, W5u16, 512, nullptr, 512, b5, nullptr, 512, 0,
                prec, hid32, cbase);
        }
    }

    // ---- epilogue: OUT = relu(hid @ WL^T + base[n] + bout)  (A is f32) ----
    gemm_kernel<2, float, false><<<dim3(NR / 128, 512 / 128, 1), 256, 0, stream>>>(
        hid32, 512, WL16, 512, OUT16, 512, bout, base, 512, 0, nullptr, nullptr, 0);

    // ---- classifier: split-K over 151 chunks of 512 ----
    prep_wcls<<<dim3((C_ * H_) / 256, 256), 256, 0, stream>>>(wcls, Wcls16);
    gemm_kernel<0, _Float16, false><<<dim3(NOBJ / 128, 256 / 128, C_), 256, 0, stream>>>(
        OUT16, C_ * H_, Wcls16, C_ * H_, partial, 256, nullptr, nullptr, 512, NOBJ * 256,
        nullptr, nullptr, 0);
    k_reduce<<<dim3(NR / 256), 256, 0, stream>>>(partial, bcls, obj);
}

// Round 8
// 3117.148 us; speedup vs baseline: 1.0308x; 1.0308x over previous
//
#include <hip/hip_runtime.h>

// ---------------------------------------------------------------------------
// GGNN-obj (N=256, C=151, H=512, T=3). Split-f16 (hi+lo) MFMA on the
// recurrent path, f32 hidden master.
// R7->R8: REVERT R7's epilogue fusions (transcendentals in a compute-bound
// GEMM epilogue cost +25us/dispatch). Back to R6 structure; add adaptive
// chunking (2x128 objects when ws_size allows; else 4x64 = exact R6) and
// trim prep_wcls zero-fill.
// ---------------------------------------------------------------------------

#define C_     151
#define H_     512
#define NOBJ   256
#define NR     38656      // NOBJ * C_
#define KPAD   160        // C_ padded to 32-multiple
#define KLDS   168        // LDS row stride for transposed x tiles
#define KA     2560       // A cols in gate GEMM: [av_hi 1024 | av_lo 1024 | h 512]
#define KV     3584       // virtual K: ah*Wh + al*Wh + ah*Wl + h*Wu

typedef _Float16 half8 __attribute__((ext_vector_type(8)));
typedef _Float16 half4 __attribute__((ext_vector_type(4)));
typedef float    f32x4 __attribute__((ext_vector_type(4)));

__device__ __forceinline__ float sigm(float x) { return 1.f / (1.f + expf(-x)); }

__device__ __forceinline__ void gload16(const void* g, void* l) {
    __builtin_amdgcn_global_load_lds(
        (const __attribute__((address_space(1))) void*)g,
        (__attribute__((address_space(3))) void*)l, 16, 0, 0);
}

__device__ __forceinline__ int kqswz(int s) {
    return 8 * (((s & 3) + 8 - ((s >> 2) & 3) - ((s >> 4) & 3)) & 3);
}
__device__ __forceinline__ int fraswz(int lane) {
    const int lb = lane & 15;
    return lb * 32 + 8 * (((lane >> 4) + lb + (lb >> 2)) & 3);
}

__device__ __forceinline__ half8 loadA8(const _Float16* p) { return *(const half8*)p; }
__device__ __forceinline__ half8 loadA8(const float* p) {
    f32x4 a = *(const f32x4*)p;
    f32x4 b = *(const f32x4*)(p + 4);
    half8 o;
    #pragma unroll
    for (int j = 0; j < 4; ++j) { o[j] = (_Float16)a[j]; o[4 + j] = (_Float16)b[j]; }
    return o;
}

// ---------------------------------------------------------------------------
// 128x128-tile GEMM (256 thr): Out[m,n] = sum_k A[m,k]*B[n,k].
// OP: 0 = f32 store, 1 = f16 store, 2 = relu(v+bias[col]+bias2[...]) -> f16
// ---------------------------------------------------------------------------
template<int OP, typename AT, bool DUPK>
__global__ __launch_bounds__(256, 2)
void gemm_kernel(const AT* __restrict__ A, int lda,
                 const _Float16* __restrict__ B, int ldb,
                 void* __restrict__ Out, int ldo,
                 const float* __restrict__ bias,
                 const float* __restrict__ bias2,
                 int kchunk, int chunkStride)
{
    constexpr bool A16 = (sizeof(AT) == 2);
    __shared__ _Float16 sA[128 * 32];
    __shared__ _Float16 sB[128 * 32];
    const int tid  = threadIdx.x;
    const int lane = tid & 63;
    const int w    = tid >> 6;
    const int m0   = blockIdx.x * 128;
    const int n0   = blockIdx.y * 128;
    const int kbase = blockIdx.z * kchunk;

    const int s0 = tid, s1 = tid + 256;
    const AT* Ap0 = A + (size_t)(m0 + (s0 >> 2)) * lda + kqswz(s0);
    const AT* Ap1 = A + (size_t)(m0 + (s1 >> 2)) * lda + kqswz(s1);
    const _Float16* Bp0 = B + (size_t)(n0 + (s0 >> 2)) * ldb + kbase + kqswz(s0);
    const _Float16* Bp1 = B + (size_t)(n0 + (s1 >> 2)) * ldb + kbase + kqswz(s1);
    const int la0 = 8 * s0;
    const int la1 = 8 * s1;
    _Float16* lA0 = &sA[w * 512];
    _Float16* lA1 = &sA[2048 + w * 512];
    _Float16* lB0 = &sB[w * 512];
    _Float16* lB1 = &sB[2048 + w * 512];

    f32x4 acc[4][4];
    #pragma unroll
    for (int i = 0; i < 4; ++i)
        #pragma unroll
        for (int j = 0; j < 4; ++j)
            #pragma unroll
            for (int r = 0; r < 4; ++r) acc[i][j][r] = 0.f;

    const int mrow = (w >> 1) * 64;
    const int ncol = (w & 1) * 64;
    const int fra  = fraswz(lane);

    for (int k0 = 0; k0 < kchunk; k0 += 32) {
        int kA;
        if (DUPK) kA = (k0 < 2048) ? k0 : ((k0 < 3072) ? k0 - 2048 : k0 - 1024);
        else      kA = kbase + k0;
        if constexpr (A16) {
            __syncthreads();
            gload16(Ap0 + kA, lA0);
            gload16(Ap1 + kA, lA1);
            gload16(Bp0 + k0, lB0);
            gload16(Bp1 + k0, lB1);
            __syncthreads();
        } else {
            half8 va0 = loadA8(Ap0 + kA);
            half8 va1 = loadA8(Ap1 + kA);
            half8 vb0 = *(const half8*)(Bp0 + k0);
            half8 vb1 = *(const half8*)(Bp1 + k0);
            __syncthreads();
            *(half8*)&sA[la0] = va0;
            *(half8*)&sA[la1] = va1;
            *(half8*)&sB[la0] = vb0;
            *(half8*)&sB[la1] = vb1;
            __syncthreads();
        }
        half8 af[4], bf[4];
        #pragma unroll
        for (int i = 0; i < 4; ++i)
            af[i] = *(const half8*)&sA[(mrow + i * 16) * 32 + fra];
        #pragma unroll
        for (int i = 0; i < 4; ++i)
            bf[i] = *(const half8*)&sB[(ncol + i * 16) * 32 + fra];
        #pragma unroll
        for (int mi = 0; mi < 4; ++mi)
            #pragma unroll
            for (int ni = 0; ni < 4; ++ni)
                acc[mi][ni] = __builtin_amdgcn_mfma_f32_16x16x32_f16(af[mi], bf[ni], acc[mi][ni], 0, 0, 0);
    }

    const size_t zoff = (size_t)blockIdx.z * (size_t)chunkStride;
    #pragma unroll
    for (int mi = 0; mi < 4; ++mi) {
        #pragma unroll
        for (int ni = 0; ni < 4; ++ni) {
            #pragma unroll
            for (int r = 0; r < 4; ++r) {
                const int row = m0 + mrow + mi * 16 + (lane >> 4) * 4 + r;
                const int col = n0 + ncol + ni * 16 + (lane & 15);
                float v = acc[mi][ni][r];
                const size_t o = zoff + (size_t)row * ldo + col;
                if (OP == 0) {
                    ((float*)Out)[o] = v;
                } else if (OP == 1) {
                    ((_Float16*)Out)[o] = (_Float16)v;
                } else {
                    const unsigned n = (unsigned)row / 151u;
                    v += bias[col] + bias2[n * 512u + col];
                    v = v > 0.f ? v : 0.f;
                    ((_Float16*)Out)[o] = (_Float16)v;
                }
            }
        }
    }
}

// ---------------------------------------------------------------------------
// 128(M)x256(N)-tile GEMM, 512 threads = 8 waves of 64x64. f16 A, DMA staging.
// ---------------------------------------------------------------------------
template<int OP, bool DUPK>
__global__ __launch_bounds__(512, 2)
void gemm_wide(const _Float16* __restrict__ A, int lda,
               const _Float16* __restrict__ B, int ldb,
               void* __restrict__ Out, int ldo,
               int kchunk, int chunkStride)
{
    __shared__ _Float16 sA[128 * 32];
    __shared__ _Float16 sB[256 * 32];
    const int tid  = threadIdx.x;
    const int lane = tid & 63;
    const int w    = tid >> 6;              // 0..7
    const int m0   = blockIdx.x * 128;
    const int n0   = blockIdx.y * 256;
    const int kbase = blockIdx.z * kchunk;

    const int kq = kqswz(tid);
    const _Float16* Ap = A + (size_t)(m0 + (tid >> 2)) * lda + kq;
    const _Float16* Bp0 = B + (size_t)(n0 + (tid >> 2)) * ldb + kbase + kq;
    const _Float16* Bp1 = B + (size_t)(n0 + 128 + (tid >> 2)) * ldb + kbase + kq;
    _Float16* lA  = &sA[w * 512];
    _Float16* lB0 = &sB[w * 512];
    _Float16* lB1 = &sB[4096 + w * 512];

    f32x4 acc[4][4];
    #pragma unroll
    for (int i = 0; i < 4; ++i)
        #pragma unroll
        for (int j = 0; j < 4; ++j)
            #pragma unroll
            for (int r = 0; r < 4; ++r) acc[i][j][r] = 0.f;

    const int mrow = (w >> 2) * 64;
    const int ncol = (w & 3) * 64;
    const int fra  = fraswz(lane);

    for (int k0 = 0; k0 < kchunk; k0 += 32) {
        int kA;
        if (DUPK) kA = (k0 < 2048) ? k0 : ((k0 < 3072) ? k0 - 2048 : k0 - 1024);
        else      kA = kbase + k0;
        __syncthreads();
        gload16(Ap + kA, lA);
        gload16(Bp0 + k0, lB0);
        gload16(Bp1 + k0, lB1);
        __syncthreads();
        half8 af[4], bf[4];
        #pragma unroll
        for (int i = 0; i < 4; ++i)
            af[i] = *(const half8*)&sA[(mrow + i * 16) * 32 + fra];
        #pragma unroll
        for (int i = 0; i < 4; ++i)
            bf[i] = *(const half8*)&sB[(ncol + i * 16) * 32 + fra];
        #pragma unroll
        for (int mi = 0; mi < 4; ++mi)
            #pragma unroll
            for (int ni = 0; ni < 4; ++ni)
                acc[mi][ni] = __builtin_amdgcn_mfma_f32_16x16x32_f16(af[mi], bf[ni], acc[mi][ni], 0, 0, 0);
    }

    const size_t zoff = (size_t)blockIdx.z * (size_t)chunkStride;
    #pragma unroll
    for (int mi = 0; mi < 4; ++mi) {
        #pragma unroll
        for (int ni = 0; ni < 4; ++ni) {
            #pragma unroll
            for (int r = 0; r < 4; ++r) {
                const int row = m0 + mrow + mi * 16 + (lane >> 4) * 4 + r;
                const int col = n0 + ncol + ni * 16 + (lane & 15);
                const float v = acc[mi][ni][r];
                const size_t o = zoff + (size_t)row * ldo + col;
                if (OP == 0) ((float*)Out)[o] = v;
                else         ((_Float16*)Out)[o] = (_Float16)v;
            }
        }
    }
}

// ---------------------------------------------------------------------------
// Mix kernel (one object chunk), split precision, xcast fused.
// ---------------------------------------------------------------------------
__global__ __launch_bounds__(256, 2)
void mix_kernel(const float* __restrict__ hid, const float* __restrict__ S,
                const _Float16* __restrict__ MTh, const _Float16* __restrict__ MTl,
                const _Float16* __restrict__ Mrh, const _Float16* __restrict__ Mrl,
                _Float16* __restrict__ AVH, int cbase)
{
    __shared__ _Float16 sxh[64 * KLDS];
    __shared__ _Float16 sxl[64 * KLDS];
    const int n  = blockIdx.x;
    const int h0 = blockIdx.y * 64;
    const int tid = threadIdx.x;

    #pragma unroll
    for (int i = 0; i < 5; ++i) {
        const int s  = tid + 256 * i;          // 0..1279
        const int c  = s >> 3;                 // 0..159
        const int hg = s & 7;
        half8 oh, ol;
        if (c < C_) {
            const float* hp = &hid[(size_t)(cbase + n * C_ + c) * H_ + h0 + hg * 8];
            const float* sp = &S[c * H_ + h0 + hg * 8];
            half8 hh;
            #pragma unroll
            for (int j = 0; j < 8; ++j) {
                const float hv = hp[j];
                const float x = sp[j] - hv;
                const _Float16 hi = (_Float16)x;
                oh[j] = hi;
                ol[j] = (_Float16)(x - (float)hi);
                hh[j] = (_Float16)hv;
            }
            *(half8*)&AVH[(size_t)(n * C_ + c) * KA + 2048 + h0 + hg * 8] = hh;
        } else {
            #pragma unroll
            for (int j = 0; j < 8; ++j) { oh[j] = (_Float16)0.f; ol[j] = (_Float16)0.f; }
        }
        #pragma unroll
        for (int j = 0; j < 8; ++j) {
            sxh[(hg * 8 + j) * KLDS + c] = oh[j];
            sxl[(hg * 8 + j) * KLDS + c] = ol[j];
        }
    }
    __syncthreads();

    const int lane = tid & 63;
    const int w    = tid >> 6;
    const _Float16* Mhi = (w >> 1) ? Mrh : MTh;
    const _Float16* Mlo = (w >> 1) ? Mrl : MTl;
    const int hb = (w & 1) * 32;

    f32x4 acc[10][2];
    #pragma unroll
    for (int i = 0; i < 10; ++i)
        #pragma unroll
        for (int j = 0; j < 2; ++j)
            #pragma unroll
            for (int r = 0; r < 4; ++r) acc[i][j][r] = 0.f;

    #pragma unroll
    for (int pass = 0; pass < 3; ++pass) {
        const _Float16* Ma = (pass == 2) ? Mlo : Mhi;
        const _Float16* X  = (pass == 1) ? sxl : sxh;
        #pragma unroll
        for (int kk = 0; kk < 5; ++kk) {
            const int k0 = kk * 32;
            half8 bf[2];
            #pragma unroll
            for (int ht = 0; ht < 2; ++ht)
                bf[ht] = *(const half8*)&X[(hb + ht * 16 + (lane & 15)) * KLDS + k0 + 8 * (lane >> 4)];
            #pragma unroll
            for (int dt = 0; dt < 10; ++dt) {
                half8 af = *(const half8*)&Ma[(dt * 16 + (lane & 15)) * KPAD + k0 + 8 * (lane >> 4)];
                acc[dt][0] = __builtin_amdgcn_mfma_f32_16x16x32_f16(af, bf[0], acc[dt][0], 0, 0, 0);
                acc[dt][1] = __builtin_amdgcn_mfma_f32_16x16x32_f16(af, bf[1], acc[dt][1], 0, 0, 0);
            }
        }
    }

    const int mixoff = (w >> 1) * 512;
    #pragma unroll
    for (int dt = 0; dt < 10; ++dt) {
        #pragma unroll
        for (int ht = 0; ht < 2; ++ht) {
            #pragma unroll
            for (int r = 0; r < 4; ++r) {
                const int d = dt * 16 + (lane >> 4) * 4 + r;
                if (d < C_) {
                    const int h = h0 + hb + ht * 16 + (lane & 15);
                    const float v = acc[dt][ht][r];
                    const _Float16 hi = (_Float16)v;
                    const _Float16 lo = (_Float16)(v - (float)hi);
                    _Float16* rowp = AVH + (size_t)(n * C_ + d) * KA + mixoff + h;
                    rowp[0]    = hi;
                    rowp[1024] = lo;
                }
            }
        }
    }
}

// --------------------------- small kernels ---------------------------------

__global__ void k_sreduce(const float* __restrict__ hid, float* __restrict__ Stmp)
{
    const int c  = blockIdx.x;      // 151
    const int g  = blockIdx.y;      // 8
    const int hw = threadIdx.x;     // 64
    const float* p = hid + (size_t)c * H_ + hw * 8;
    float s[8];
    #pragma unroll
    for (int j = 0; j < 8; ++j) s[j] = 0.f;
    const size_t stride = (size_t)C_ * H_;
    for (int n = g * 32; n < g * 32 + 32; ++n) {
        f32x4 a = *(const f32x4*)(p + (size_t)n * stride);
        f32x4 b = *(const f32x4*)(p + (size_t)n * stride + 4);
        #pragma unroll
        for (int j = 0; j < 4; ++j) { s[j] += a[j]; s[4 + j] += b[j]; }
    }
    float* o = Stmp + (size_t)g * (C_ * H_) + c * H_ + hw * 8;
    *(f32x4*)o       = f32x4{s[0], s[1], s[2], s[3]};
    *(f32x4*)(o + 4) = f32x4{s[4], s[5], s[6], s[7]};
}

__global__ void k_sfold(const float* __restrict__ Stmp, float* __restrict__ S)
{
    const int idx = blockIdx.x * 256 + threadIdx.x;   // 77312
    float s = 0.f;
    #pragma unroll
    for (int g = 0; g < 8; ++g) s += Stmp[(size_t)g * (C_ * H_) + idx];
    S[idx] = s;
}

__global__ void k_ew1(_Float16* __restrict__ pre, const float* __restrict__ hid,
                      const float* __restrict__ bz, const float* __restrict__ br, int cbase)
{
    const int idx = blockIdx.x * 256 + threadIdx.x;   // CH*128
    const unsigned r = idx >> 7;
    const int o4 = (idx & 127) << 2;
    const size_t base = (size_t)r * 1536;
    half4 zp = *(const half4*)&pre[base + o4];
    half4 rp = *(const half4*)&pre[base + 512 + o4];
    f32x4 hd = *(const f32x4*)&hid[(size_t)(cbase + r) * H_ + o4];
    f32x4 bz4 = *(const f32x4*)&bz[o4];
    f32x4 br4 = *(const f32x4*)&br[o4];
    half4 zs, rh;
    #pragma unroll
    for (int j = 0; j < 4; ++j) {
        float z = sigm((float)zp[j] + bz4[j]);
        float rr = sigm((float)rp[j] + br4[j]);
        zs[j] = (_Float16)z;
        rh[j] = (_Float16)(rr * hd[j]);
    }
    *(half4*)&pre[base + o4] = zs;
    *(half4*)&pre[base + 512 + o4] = rh;
}

// EW2: hv = tanh(pre_w5 + p5a + p5b + b5); h = (1-z)h + z*hv -> hid (f32)
__global__ void k_ew2(const _Float16* __restrict__ pre, const _Float16* __restrict__ p5a,
                      const _Float16* __restrict__ p5b,
                      float* __restrict__ hid, const float* __restrict__ b5, int cbase)
{
    const int idx = blockIdx.x * 256 + threadIdx.x;   // CH*128
    const unsigned r = idx >> 7;
    const int o4 = (idx & 127) << 2;
    const size_t base = (size_t)r * 1536;
    half4 w5 = *(const half4*)&pre[base + 1024 + o4];
    half4 pa = *(const half4*)&p5a[(size_t)r * H_ + o4];
    half4 pb = *(const half4*)&p5b[(size_t)r * H_ + o4];
    half4 zz = *(const half4*)&pre[base + o4];
    f32x4 hd = *(const f32x4*)&hid[(size_t)(cbase + r) * H_ + o4];
    f32x4 b54 = *(const f32x4*)&b5[o4];
    #pragma unroll
    for (int j = 0; j < 4; ++j) {
        float t = tanhf((float)w5[j] + (float)pa[j] + (float)pb[j] + b54[j]);
        float z = (float)zz[j];
        hd[j] = (1.f - z) * hd[j] + z * t;
    }
    *(f32x4*)&hid[(size_t)(cbase + r) * H_ + o4] = hd;
}

// --------------------------- prep kernels ----------------------------------

__global__ void prep_wbig(const float* w3w, const float* w3u,
                          const float* w4w, const float* w4u,
                          const float* w5w, const float* w5u,
                          _Float16* __restrict__ Wbig)
{
    const int idx = blockIdx.x * 256 + threadIdx.x;   // 1536*3584
    const int op = idx / KV;
    const int j = idx - op * KV;
    const int g = op >> 9, o = op & 511;
    const float* ww = (g == 0) ? w3w : (g == 1) ? w4w : w5w;
    const float* wu = (g == 0) ? w3u : (g == 1) ? w4u : w5u;
    _Float16 out;
    if (j < 1024) {
        out = (_Float16)ww[o * 1024 + j];
    } else if (j < 2048) {
        out = (_Float16)ww[o * 1024 + (j - 1024)];
    } else if (j < 3072) {
        const float v = ww[o * 1024 + (j - 2048)];
        const _Float16 hi = (_Float16)v;
        out = (_Float16)(v - (float)hi);
    } else {
        out = (g < 2) ? (_Float16)wu[o * 512 + (j - 3072)] : (_Float16)0.f;
    }
    Wbig[idx] = out;
}

__global__ void prep_m(const float* __restrict__ matrix,
                       _Float16* __restrict__ MTh, _Float16* __restrict__ MTl,
                       _Float16* __restrict__ Mrh, _Float16* __restrict__ Mrl)
{
    const int idx = blockIdx.x * 256 + threadIdx.x;   // KPAD*KPAD
    const int d = idx / KPAD, c = idx - d * KPAD;
    float vT = 0.f, vR = 0.f;
    if (d < C_ && c < C_) { vT = matrix[c * C_ + d]; vR = matrix[d * C_ + c]; }
    const _Float16 th = (_Float16)vT;
    const _Float16 rh = (_Float16)vR;
    MTh[idx] = th; MTl[idx] = (_Float16)(vT - (float)th);
    Mrh[idx] = rh; Mrl[idx] = (_Float16)(vR - (float)rh);
}

__global__ void prep_wout(const float* __restrict__ wout,
                          _Float16* __restrict__ WL, _Float16* __restrict__ WR)
{
    const int idx = blockIdx.x * 256 + threadIdx.x;   // 512*512
    const int o = idx >> 9, j = idx & 511;
    WL[idx] = (_Float16)wout[o * 1024 + j];
    WR[idx] = (_Float16)wout[o * 1024 + 512 + j];
}

// only the 151 real rows; rows 151..255 stay poisoned (never read downstream)
__global__ void prep_wcls(const float* __restrict__ wcls, _Float16* __restrict__ w16)
{
    const int k = blockIdx.x * 256 + threadIdx.x;   // 77312
    const int d = blockIdx.y;                        // 0..150
    w16[(size_t)d * (C_ * H_) + k] = (_Float16)wcls[(size_t)d * (C_ * H_) + k];
}

__global__ void k_cast(const float* __restrict__ src, _Float16* __restrict__ dst, int n)
{
    const int i = blockIdx.x * 256 + threadIdx.x;
    if (i < n) dst[i] = (_Float16)src[i];
}

__global__ void prep_bias(const float* b3w, const float* b3u, const float* b4w,
                          const float* b4u, const float* b5w, const float* b5u,
                          float* bz, float* br, float* b5)
{
    const int i = threadIdx.x;   // 512 threads
    bz[i] = b3w[i] + b3u[i];
    br[i] = b4w[i] + b4u[i];
    b5[i] = b5w[i] + b5u[i];
}

__global__ void prep_hid(const float* __restrict__ input, float* __restrict__ hid)
{
    const int idx = blockIdx.x * 256 + threadIdx.x;   // NR*128
    const unsigned row = idx >> 7;
    const int h4 = (idx & 127) << 2;
    const unsigned n = row / 151u;
    f32x4 v = *(const f32x4*)&input[(size_t)n * H_ + h4];
    *(f32x4*)&hid[(size_t)row * H_ + h4] = v;
}

__global__ void k_reduce(const float* __restrict__ partial, const float* __restrict__ bcls,
                         float* __restrict__ out)
{
    const int idx = blockIdx.x * 256 + threadIdx.x;   // NR
    const unsigned n = (unsigned)idx / 151u;
    const unsigned d = (unsigned)idx - n * 151u;
    float s = 0.f;
    for (int z = 0; z < C_; ++z)
        s += partial[(size_t)z * (NOBJ * 256) + n * 256 + d];
    out[idx] = s + bcls[d];
}

// ---------------------------------------------------------------------------

extern "C" void kernel_launch(void* const* d_in, const int* in_sizes, int n_in,
                              void* d_out, int out_size, void* d_ws, size_t ws_size,
                              hipStream_t stream)
{
    const float* input  = (const float*)d_in[0];
    const float* matrix = (const float*)d_in[1];
    const float* w3w = (const float*)d_in[2];
    const float* b3w = (const float*)d_in[3];
    const float* w3u = (const float*)d_in[4];
    const float* b3u = (const float*)d_in[5];
    const float* w4w = (const float*)d_in[6];
    const float* b4w = (const float*)d_in[7];
    const float* w4u = (const float*)d_in[8];
    const float* b4u = (const float*)d_in[9];
    const float* w5w = (const float*)d_in[10];
    const float* b5w = (const float*)d_in[11];
    const float* w5u = (const float*)d_in[12];
    const float* b5u = (const float*)d_in[13];
    const float* wout = (const float*)d_in[14];
    const float* bout = (const float*)d_in[15];
    const float* wcls = (const float*)d_in[16];
    const float* bcls = (const float*)d_in[17];
    float* obj = (float*)d_out;

    // ---- adaptive chunk config (deterministic per environment) ----
    const size_t fixedBytes = (size_t)100 * 1024 * 1024;   // weights+hid32+misc, rounded up
    const size_t need2 = fixedBytes + (size_t)19328 * KA * 2 + (size_t)19328 * 1536 * 2;
    int nch, CHc, CHPc, nchunk;
    if (ws_size >= need2) { nch = 128; CHc = 19328; CHPc = 19328; nchunk = 2; }
    else                  { nch = 64;  CHc = 9664;  CHPc = 9728;  nchunk = 4; }

    char* ws = (char*)d_ws;
    size_t off = 0;
    auto take = [&](size_t bytes) -> char* {
        off = (off + 255) & ~(size_t)255;
        char* p = ws + off;
        off += bytes;
        return p;
    };

    _Float16* Wbig  = (_Float16*)take((size_t)1536 * KV * 2);     // 11.01 MB
    _Float16* MTh   = (_Float16*)take((size_t)KPAD * KPAD * 2);
    _Float16* MTl   = (_Float16*)take((size_t)KPAD * KPAD * 2);
    _Float16* Mrh   = (_Float16*)take((size_t)KPAD * KPAD * 2);
    _Float16* Mrl   = (_Float16*)take((size_t)KPAD * KPAD * 2);
    _Float16* W5u16 = (_Float16*)take((size_t)512 * 512 * 2);
    _Float16* WL16  = (_Float16*)take((size_t)512 * 512 * 2);
    _Float16* WR16  = (_Float16*)take((size_t)512 * 512 * 2);
    _Float16* in16  = (_Float16*)take((size_t)256 * 512 * 2);
    float*    bz    = (float*)take(512 * 4);
    float*    br    = (float*)take(512 * 4);
    float*    b5    = (float*)take(512 * 4);
    float*    Stmp  = (float*)take((size_t)8 * C_ * H_ * 4);      //  2.47 MB
    float*    S32   = (float*)take((size_t)C_ * H_ * 4);
    float*    base  = (float*)take((size_t)256 * 512 * 4);
    float*    hid32 = (float*)take((size_t)NR * H_ * 4);          // 79.17 MB
    _Float16* AVH   = (_Float16*)take((size_t)CHPc * KA * 2);
    _Float16* prec  = (_Float16*)take((size_t)CHPc * 1536 * 2);
    // time-based aliases:
    _Float16* p5u = AVH;                 // 2 split-K halves: 2*CHPc*512*2 <= AVH bytes
    _Float16* OUT16 = AVH;               // epilogue out (after loop)
    _Float16* Wcls16 = (_Float16*)hid32; // hid dead after epilogue GEMM
    float* partial = (float*)((char*)hid32 + (size_t)NOBJ * C_ * H_ * 2);

    (void)in_sizes; (void)n_in; (void)out_size;

    // ---- prep ----
    prep_wbig<<<dim3((1536 * KV) / 256), 256, 0, stream>>>(w3w, w3u, w4w, w4u, w5w, w5u, Wbig);
    prep_m<<<dim3((KPAD * KPAD) / 256), 256, 0, stream>>>(matrix, MTh, MTl, Mrh, Mrl);
    k_cast<<<dim3((512 * 512) / 256), 256, 0, stream>>>(w5u, W5u16, 512 * 512);
    prep_wout<<<dim3((512 * 512) / 256), 256, 0, stream>>>(wout, WL16, WR16);
    k_cast<<<dim3((256 * 512) / 256), 256, 0, stream>>>(input, in16, 256 * 512);
    prep_bias<<<dim3(1), 512, 0, stream>>>(b3w, b3u, b4w, b4u, b5w, b5u, bz, br, b5);
    prep_hid<<<dim3((NR * 128) / 256), 256, 0, stream>>>(input, hid32);
    gemm_kernel<0, _Float16, false><<<dim3(2, 4, 1), 256, 0, stream>>>(
        in16, 512, WR16, 512, base, 512, nullptr, nullptr, 512, 0);

    // ---- 3 GGNN steps ----
    for (int t = 0; t < 3; ++t) {
        k_sreduce<<<dim3(C_, 8), 64, 0, stream>>>(hid32, Stmp);
        k_sfold<<<dim3((C_ * H_) / 256), 256, 0, stream>>>(Stmp, S32);
        for (int cc = 0; cc < nchunk; ++cc) {
            const int cbase = cc * CHc;
            mix_kernel<<<dim3(nch, 8), 256, 0, stream>>>(
                hid32, S32, MTh, MTl, Mrh, Mrl, AVH, cbase);
            // gate GEMM (virtual K=3584), 128x256 tiles
            gemm_wide<1, true><<<dim3(CHPc / 128, 1536 / 256, 1), 512, 0, stream>>>(
                AVH, KA, Wbig, KV, prec, 1536, KV, 0);
            k_ew1<<<dim3(CHc / 2), 256, 0, stream>>>(prec, hid32, bz, br, cbase);
            // p5u = (r*h) @ W5u^T, split-K=2 (f16 partials summed in ew2)
            gemm_kernel<1, _Float16, false><<<dim3(CHPc / 128, 4, 2), 256, 0, stream>>>(
                prec + 512, 1536, W5u16, 512, p5u, 512, nullptr, nullptr, 256,
                CHPc * 512);
            k_ew2<<<dim3(CHc / 2), 256, 0, stream>>>(
                prec, p5u, p5u + (size_t)CHPc * 512, hid32, b5, cbase);
        }
    }

    // ---- epilogue: OUT = relu(hid @ WL^T + base[n] + bout)  (A is f32) ----
    gemm_kernel<2, float, false><<<dim3(NR / 128, 512 / 128, 1), 256, 0, stream>>>(
        hid32, 512, WL16, 512, OUT16, 512, bout, base, 512, 0);

    // ---- classifier: split-K over 151 chunks of 512 ----
    prep_wcls<<<dim3((C_ * H_) / 256, C_), 256, 0, stream>>>(wcls, Wcls16);
    gemm_kernel<0, _Float16, false><<<dim3(NOBJ / 128, 256 / 128, C_), 256, 0, stream>>>(
        OUT16, C_ * H_, Wcls16, C_ * H_, partial, 256, nullptr, nullptr, 512, NOBJ * 256);
    k_reduce<<<dim3(NR / 256), 256, 0, stream>>>(partial, bcls, obj);
}

// Round 9
// 2861.686 us; speedup vs baseline: 1.1228x; 1.0893x over previous
//
#include <hip/hip_runtime.h>

// ---------------------------------------------------------------------------
// GGNN-obj (N=256, C=151, H=512, T=3). Split-f16 (hi+lo) MFMA on the
// recurrent path, f32 hidden master.
// R8->R9: revert to fixed 4x64 object chunks (2x128 lost L3 A-residency:
// FETCH 111->456 MB). Gate GEMM (gemm_wide) switched to 32x32x16 MFMA
// (~15% higher per-inst throughput, m119: 2495 vs 2176 TF; half the MFMA
// instructions, same LDS traffic). gemm_kernel stays 16x16x32 (memory-bound
// uses). A/B frag: m|n = lane&31, k = 8*(lane>>5)+j; C/D: col=lane&31,
// row=(reg&3)+8*(reg>>2)+4*(lane>>5) [m74/m101].
// ---------------------------------------------------------------------------

#define C_     151
#define H_     512
#define NOBJ   256
#define NR     38656      // NOBJ * C_
#define NCH    64         // objects per chunk
#define CH     9664       // NCH * C_
#define CHP    9728       // CH padded to 128-multiple (76 tiles)
#define KPAD   160        // C_ padded to 32-multiple
#define KLDS   168        // LDS row stride for transposed x tiles
#define KA     2560       // A cols in gate GEMM: [av_hi 1024 | av_lo 1024 | h 512]
#define KV     3584       // virtual K: ah*Wh + al*Wh + ah*Wl + h*Wu

typedef _Float16 half8 __attribute__((ext_vector_type(8)));
typedef _Float16 half4 __attribute__((ext_vector_type(4)));
typedef float    f32x4 __attribute__((ext_vector_type(4)));
typedef float    f32x16 __attribute__((ext_vector_type(16)));

__device__ __forceinline__ float sigm(float x) { return 1.f / (1.f + expf(-x)); }

__device__ __forceinline__ void gload16(const void* g, void* l) {
    __builtin_amdgcn_global_load_lds(
        (const __attribute__((address_space(1))) void*)g,
        (__attribute__((address_space(3))) void*)l, 16, 0, 0);
}

// Staging swizzle: LDS slot (row r, phys group p) holds logical k-group
// (p - r - (r>>2)) & 3; staging slot s fetches global k-offset kqswz(s).
__device__ __forceinline__ int kqswz(int s) {
    return 8 * (((s & 3) + 8 - ((s >> 2) & 3) - ((s >> 4) & 3)) & 3);
}
// 16x16 fragment read offset (row base multiple of 16):
__device__ __forceinline__ int fraswz(int lane) {
    const int lb = lane & 15;
    return lb * 32 + 8 * (((lane >> 4) + lb + (lb >> 2)) & 3);
}

__device__ __forceinline__ half8 loadA8(const _Float16* p) { return *(const half8*)p; }
__device__ __forceinline__ half8 loadA8(const float* p) {
    f32x4 a = *(const f32x4*)p;
    f32x4 b = *(const f32x4*)(p + 4);
    half8 o;
    #pragma unroll
    for (int j = 0; j < 4; ++j) { o[j] = (_Float16)a[j]; o[4 + j] = (_Float16)b[j]; }
    return o;
}

// ---------------------------------------------------------------------------
// 128x128-tile GEMM (256 thr, 16x16x32): Out[m,n] = sum_k A[m,k]*B[n,k].
// OP: 0 = f32 store, 1 = f16 store, 2 = relu(v+bias[col]+bias2[...]) -> f16
// ---------------------------------------------------------------------------
template<int OP, typename AT, bool DUPK>
__global__ __launch_bounds__(256, 2)
void gemm_kernel(const AT* __restrict__ A, int lda,
                 const _Float16* __restrict__ B, int ldb,
                 void* __restrict__ Out, int ldo,
                 const float* __restrict__ bias,
                 const float* __restrict__ bias2,
                 int kchunk, int chunkStride)
{
    constexpr bool A16 = (sizeof(AT) == 2);
    __shared__ _Float16 sA[128 * 32];
    __shared__ _Float16 sB[128 * 32];
    const int tid  = threadIdx.x;
    const int lane = tid & 63;
    const int w    = tid >> 6;
    const int m0   = blockIdx.x * 128;
    const int n0   = blockIdx.y * 128;
    const int kbase = blockIdx.z * kchunk;

    const int s0 = tid, s1 = tid + 256;
    const AT* Ap0 = A + (size_t)(m0 + (s0 >> 2)) * lda + kqswz(s0);
    const AT* Ap1 = A + (size_t)(m0 + (s1 >> 2)) * lda + kqswz(s1);
    const _Float16* Bp0 = B + (size_t)(n0 + (s0 >> 2)) * ldb + kbase + kqswz(s0);
    const _Float16* Bp1 = B + (size_t)(n0 + (s1 >> 2)) * ldb + kbase + kqswz(s1);
    const int la0 = 8 * s0;
    const int la1 = 8 * s1;
    _Float16* lA0 = &sA[w * 512];
    _Float16* lA1 = &sA[2048 + w * 512];
    _Float16* lB0 = &sB[w * 512];
    _Float16* lB1 = &sB[2048 + w * 512];

    f32x4 acc[4][4];
    #pragma unroll
    for (int i = 0; i < 4; ++i)
        #pragma unroll
        for (int j = 0; j < 4; ++j)
            #pragma unroll
            for (int r = 0; r < 4; ++r) acc[i][j][r] = 0.f;

    const int mrow = (w >> 1) * 64;
    const int ncol = (w & 1) * 64;
    const int fra  = fraswz(lane);

    for (int k0 = 0; k0 < kchunk; k0 += 32) {
        int kA;
        if (DUPK) kA = (k0 < 2048) ? k0 : ((k0 < 3072) ? k0 - 2048 : k0 - 1024);
        else      kA = kbase + k0;
        if constexpr (A16) {
            __syncthreads();
            gload16(Ap0 + kA, lA0);
            gload16(Ap1 + kA, lA1);
            gload16(Bp0 + k0, lB0);
            gload16(Bp1 + k0, lB1);
            __syncthreads();
        } else {
            half8 va0 = loadA8(Ap0 + kA);
            half8 va1 = loadA8(Ap1 + kA);
            half8 vb0 = *(const half8*)(Bp0 + k0);
            half8 vb1 = *(const half8*)(Bp1 + k0);
            __syncthreads();
            *(half8*)&sA[la0] = va0;
            *(half8*)&sA[la1] = va1;
            *(half8*)&sB[la0] = vb0;
            *(half8*)&sB[la1] = vb1;
            __syncthreads();
        }
        half8 af[4], bf[4];
        #pragma unroll
        for (int i = 0; i < 4; ++i)
            af[i] = *(const half8*)&sA[(mrow + i * 16) * 32 + fra];
        #pragma unroll
        for (int i = 0; i < 4; ++i)
            bf[i] = *(const half8*)&sB[(ncol + i * 16) * 32 + fra];
        #pragma unroll
        for (int mi = 0; mi < 4; ++mi)
            #pragma unroll
            for (int ni = 0; ni < 4; ++ni)
                acc[mi][ni] = __builtin_amdgcn_mfma_f32_16x16x32_f16(af[mi], bf[ni], acc[mi][ni], 0, 0, 0);
    }

    const size_t zoff = (size_t)blockIdx.z * (size_t)chunkStride;
    #pragma unroll
    for (int mi = 0; mi < 4; ++mi) {
        #pragma unroll
        for (int ni = 0; ni < 4; ++ni) {
            #pragma unroll
            for (int r = 0; r < 4; ++r) {
                const int row = m0 + mrow + mi * 16 + (lane >> 4) * 4 + r;
                const int col = n0 + ncol + ni * 16 + (lane & 15);
                float v = acc[mi][ni][r];
                const size_t o = zoff + (size_t)row * ldo + col;
                if (OP == 0) {
                    ((float*)Out)[o] = v;
                } else if (OP == 1) {
                    ((_Float16*)Out)[o] = (_Float16)v;
                } else {
                    const unsigned n = (unsigned)row / 151u;
                    v += bias[col] + bias2[n * 512u + col];
                    v = v > 0.f ? v : 0.f;
                    ((_Float16*)Out)[o] = (_Float16)v;
                }
            }
        }
    }
}

// ---------------------------------------------------------------------------
// 128(M)x256(N)-tile GEMM, 512 thr = 8 waves of 64x64, 32x32x16 MFMA.
// Each wave: 2x2 grid of 32x32 tiles; 2 MFMAs (k 0:16,16:32) per tile per
// staging iter. Staging identical to before (layout/swizzle unchanged).
// ---------------------------------------------------------------------------
template<int OP, bool DUPK>
__global__ __launch_bounds__(512, 2)
void gemm_wide(const _Float16* __restrict__ A, int lda,
               const _Float16* __restrict__ B, int ldb,
               void* __restrict__ Out, int ldo,
               int kchunk, int chunkStride)
{
    __shared__ _Float16 sA[128 * 32];
    __shared__ _Float16 sB[256 * 32];
    const int tid  = threadIdx.x;
    const int lane = tid & 63;
    const int w    = tid >> 6;              // 0..7
    const int m0   = blockIdx.x * 128;
    const int n0   = blockIdx.y * 256;
    const int kbase = blockIdx.z * kchunk;

    const int kq = kqswz(tid);
    const _Float16* Ap = A + (size_t)(m0 + (tid >> 2)) * lda + kq;
    const _Float16* Bp0 = B + (size_t)(n0 + (tid >> 2)) * ldb + kbase + kq;
    const _Float16* Bp1 = B + (size_t)(n0 + 128 + (tid >> 2)) * ldb + kbase + kq;
    _Float16* lA  = &sA[w * 512];
    _Float16* lB0 = &sB[w * 512];
    _Float16* lB1 = &sB[4096 + w * 512];

    f32x16 acc[2][2];
    #pragma unroll
    for (int i = 0; i < 2; ++i)
        #pragma unroll
        for (int j = 0; j < 2; ++j)
            #pragma unroll
            for (int r = 0; r < 16; ++r) acc[i][j][r] = 0.f;

    const int mrow = (w >> 2) * 64;          // 2 M-slices
    const int ncol = (w & 3) * 64;           // 4 N-slices
    const int l31  = lane & 31;
    const int khi  = lane >> 5;              // 0/1
    // physical k-group offset (halves) for logical group g = 2q + khi at row
    // ... + l31 (row base multiples of 32 -> low 5 row bits come from l31):
    int poff[2];
    #pragma unroll
    for (int q = 0; q < 2; ++q)
        poff[q] = 8 * (((2 * q + khi) + (l31 & 3) + ((l31 >> 2) & 3)) & 3);

    for (int k0 = 0; k0 < kchunk; k0 += 32) {
        int kA;
        if (DUPK) kA = (k0 < 2048) ? k0 : ((k0 < 3072) ? k0 - 2048 : k0 - 1024);
        else      kA = kbase + k0;
        __syncthreads();
        gload16(Ap + kA, lA);
        gload16(Bp0 + k0, lB0);
        gload16(Bp1 + k0, lB1);
        __syncthreads();
        half8 af[2][2], bf[2][2];            // [q][tile]
        #pragma unroll
        for (int q = 0; q < 2; ++q) {
            #pragma unroll
            for (int mi = 0; mi < 2; ++mi)
                af[q][mi] = *(const half8*)&sA[(mrow + mi * 32 + l31) * 32 + poff[q]];
            #pragma unroll
            for (int ni = 0; ni < 2; ++ni)
                bf[q][ni] = *(const half8*)&sB[(ncol + ni * 32 + l31) * 32 + poff[q]];
        }
        #pragma unroll
        for (int mi = 0; mi < 2; ++mi)
            #pragma unroll
            for (int ni = 0; ni < 2; ++ni) {
                acc[mi][ni] = __builtin_amdgcn_mfma_f32_32x32x16_f16(af[0][mi], bf[0][ni], acc[mi][ni], 0, 0, 0);
                acc[mi][ni] = __builtin_amdgcn_mfma_f32_32x32x16_f16(af[1][mi], bf[1][ni], acc[mi][ni], 0, 0, 0);
            }
    }

    const size_t zoff = (size_t)blockIdx.z * (size_t)chunkStride;
    #pragma unroll
    for (int mi = 0; mi < 2; ++mi) {
        #pragma unroll
        for (int ni = 0; ni < 2; ++ni) {
            #pragma unroll
            for (int rv = 0; rv < 4; ++rv) {
                #pragma unroll
                for (int ri = 0; ri < 4; ++ri) {
                    const int row = m0 + mrow + mi * 32 + ri + 8 * rv + 4 * khi;
                    const int col = n0 + ncol + ni * 32 + l31;
                    const float v = acc[mi][ni][rv * 4 + ri];
                    const size_t o = zoff + (size_t)row * ldo + col;
                    if (OP == 0) ((float*)Out)[o] = v;
                    else         ((_Float16*)Out)[o] = (_Float16)v;
                }
            }
        }
    }
}

// ---------------------------------------------------------------------------
// Mix kernel (one 64-object chunk), split precision, xcast fused.
// ---------------------------------------------------------------------------
__global__ __launch_bounds__(256, 2)
void mix_kernel(const float* __restrict__ hid, const float* __restrict__ S,
                const _Float16* __restrict__ MTh, const _Float16* __restrict__ MTl,
                const _Float16* __restrict__ Mrh, const _Float16* __restrict__ Mrl,
                _Float16* __restrict__ AVH, int cbase)
{
    __shared__ _Float16 sxh[64 * KLDS];
    __shared__ _Float16 sxl[64 * KLDS];
    const int n  = blockIdx.x;
    const int h0 = blockIdx.y * 64;
    const int tid = threadIdx.x;

    #pragma unroll
    for (int i = 0; i < 5; ++i) {
        const int s  = tid + 256 * i;          // 0..1279
        const int c  = s >> 3;                 // 0..159
        const int hg = s & 7;
        half8 oh, ol;
        if (c < C_) {
            const float* hp = &hid[(size_t)(cbase + n * C_ + c) * H_ + h0 + hg * 8];
            const float* sp = &S[c * H_ + h0 + hg * 8];
            half8 hh;
            #pragma unroll
            for (int j = 0; j < 8; ++j) {
                const float hv = hp[j];
                const float x = sp[j] - hv;
                const _Float16 hi = (_Float16)x;
                oh[j] = hi;
                ol[j] = (_Float16)(x - (float)hi);
                hh[j] = (_Float16)hv;
            }
            *(half8*)&AVH[(size_t)(n * C_ + c) * KA + 2048 + h0 + hg * 8] = hh;
        } else {
            #pragma unroll
            for (int j = 0; j < 8; ++j) { oh[j] = (_Float16)0.f; ol[j] = (_Float16)0.f; }
        }
        #pragma unroll
        for (int j = 0; j < 8; ++j) {
            sxh[(hg * 8 + j) * KLDS + c] = oh[j];
            sxl[(hg * 8 + j) * KLDS + c] = ol[j];
        }
    }
    __syncthreads();

    const int lane = tid & 63;
    const int w    = tid >> 6;
    const _Float16* Mhi = (w >> 1) ? Mrh : MTh;
    const _Float16* Mlo = (w >> 1) ? Mrl : MTl;
    const int hb = (w & 1) * 32;

    f32x4 acc[10][2];
    #pragma unroll
    for (int i = 0; i < 10; ++i)
        #pragma unroll
        for (int j = 0; j < 2; ++j)
            #pragma unroll
            for (int r = 0; r < 4; ++r) acc[i][j][r] = 0.f;

    #pragma unroll
    for (int pass = 0; pass < 3; ++pass) {
        const _Float16* Ma = (pass == 2) ? Mlo : Mhi;
        const _Float16* X  = (pass == 1) ? sxl : sxh;
        #pragma unroll
        for (int kk = 0; kk < 5; ++kk) {
            const int k0 = kk * 32;
            half8 bf[2];
            #pragma unroll
            for (int ht = 0; ht < 2; ++ht)
                bf[ht] = *(const half8*)&X[(hb + ht * 16 + (lane & 15)) * KLDS + k0 + 8 * (lane >> 4)];
            #pragma unroll
            for (int dt = 0; dt < 10; ++dt) {
                half8 af = *(const half8*)&Ma[(dt * 16 + (lane & 15)) * KPAD + k0 + 8 * (lane >> 4)];
                acc[dt][0] = __builtin_amdgcn_mfma_f32_16x16x32_f16(af, bf[0], acc[dt][0], 0, 0, 0);
                acc[dt][1] = __builtin_amdgcn_mfma_f32_16x16x32_f16(af, bf[1], acc[dt][1], 0, 0, 0);
            }
        }
    }

    const int mixoff = (w >> 1) * 512;
    #pragma unroll
    for (int dt = 0; dt < 10; ++dt) {
        #pragma unroll
        for (int ht = 0; ht < 2; ++ht) {
            #pragma unroll
            for (int r = 0; r < 4; ++r) {
                const int d = dt * 16 + (lane >> 4) * 4 + r;
                if (d < C_) {
                    const int h = h0 + hb + ht * 16 + (lane & 15);
                    const float v = acc[dt][ht][r];
                    const _Float16 hi = (_Float16)v;
                    const _Float16 lo = (_Float16)(v - (float)hi);
                    _Float16* rowp = AVH + (size_t)(n * C_ + d) * KA + mixoff + h;
                    rowp[0]    = hi;
                    rowp[1024] = lo;
                }
            }
        }
    }
}

// --------------------------- small kernels ---------------------------------

__global__ void k_sreduce(const float* __restrict__ hid, float* __restrict__ Stmp)
{
    const int c  = blockIdx.x;      // 151
    const int g  = blockIdx.y;      // 8
    const int hw = threadIdx.x;     // 64
    const float* p = hid + (size_t)c * H_ + hw * 8;
    float s[8];
    #pragma unroll
    for (int j = 0; j < 8; ++j) s[j] = 0.f;
    const size_t stride = (size_t)C_ * H_;
    for (int n = g * 32; n < g * 32 + 32; ++n) {
        f32x4 a = *(const f32x4*)(p + (size_t)n * stride);
        f32x4 b = *(const f32x4*)(p + (size_t)n * stride + 4);
        #pragma unroll
        for (int j = 0; j < 4; ++j) { s[j] += a[j]; s[4 + j] += b[j]; }
    }
    float* o = Stmp + (size_t)g * (C_ * H_) + c * H_ + hw * 8;
    *(f32x4*)o       = f32x4{s[0], s[1], s[2], s[3]};
    *(f32x4*)(o + 4) = f32x4{s[4], s[5], s[6], s[7]};
}

__global__ void k_sfold(const float* __restrict__ Stmp, float* __restrict__ S)
{
    const int idx = blockIdx.x * 256 + threadIdx.x;   // 77312
    float s = 0.f;
    #pragma unroll
    for (int g = 0; g < 8; ++g) s += Stmp[(size_t)g * (C_ * H_) + idx];
    S[idx] = s;
}

__global__ void k_ew1(_Float16* __restrict__ pre, const float* __restrict__ hid,
                      const float* __restrict__ bz, const float* __restrict__ br, int cbase)
{
    const int idx = blockIdx.x * 256 + threadIdx.x;   // CH*128
    const unsigned r = idx >> 7;
    const int o4 = (idx & 127) << 2;
    const size_t base = (size_t)r * 1536;
    half4 zp = *(const half4*)&pre[base + o4];
    half4 rp = *(const half4*)&pre[base + 512 + o4];
    f32x4 hd = *(const f32x4*)&hid[(size_t)(cbase + r) * H_ + o4];
    f32x4 bz4 = *(const f32x4*)&bz[o4];
    f32x4 br4 = *(const f32x4*)&br[o4];
    half4 zs, rh;
    #pragma unroll
    for (int j = 0; j < 4; ++j) {
        float z = sigm((float)zp[j] + bz4[j]);
        float rr = sigm((float)rp[j] + br4[j]);
        zs[j] = (_Float16)z;
        rh[j] = (_Float16)(rr * hd[j]);
    }
    *(half4*)&pre[base + o4] = zs;
    *(half4*)&pre[base + 512 + o4] = rh;
}

// EW2: hv = tanh(pre_w5 + p5a + p5b + b5); h = (1-z)h + z*hv -> hid (f32)
__global__ void k_ew2(const _Float16* __restrict__ pre, const _Float16* __restrict__ p5a,
                      const _Float16* __restrict__ p5b,
                      float* __restrict__ hid, const float* __restrict__ b5, int cbase)
{
    const int idx = blockIdx.x * 256 + threadIdx.x;   // CH*128
    const unsigned r = idx >> 7;
    const int o4 = (idx & 127) << 2;
    const size_t base = (size_t)r * 1536;
    half4 w5 = *(const half4*)&pre[base + 1024 + o4];
    half4 pa = *(const half4*)&p5a[(size_t)r * H_ + o4];
    half4 pb = *(const half4*)&p5b[(size_t)r * H_ + o4];
    half4 zz = *(const half4*)&pre[base + o4];
    f32x4 hd = *(const f32x4*)&hid[(size_t)(cbase + r) * H_ + o4];
    f32x4 b54 = *(const f32x4*)&b5[o4];
    #pragma unroll
    for (int j = 0; j < 4; ++j) {
        float t = tanhf((float)w5[j] + (float)pa[j] + (float)pb[j] + b54[j]);
        float z = (float)zz[j];
        hd[j] = (1.f - z) * hd[j] + z * t;
    }
    *(f32x4*)&hid[(size_t)(cbase + r) * H_ + o4] = hd;
}

// --------------------------- prep kernels ----------------------------------

__global__ void prep_wbig(const float* w3w, const float* w3u,
                          const float* w4w, const float* w4u,
                          const float* w5w, const float* w5u,
                          _Float16* __restrict__ Wbig)
{
    const int idx = blockIdx.x * 256 + threadIdx.x;   // 1536*3584
    const int op = idx / KV;
    const int j = idx - op * KV;
    const int g = op >> 9, o = op & 511;
    const float* ww = (g == 0) ? w3w : (g == 1) ? w4w : w5w;
    const float* wu = (g == 0) ? w3u : (g == 1) ? w4u : w5u;
    _Float16 out;
    if (j < 1024) {
        out = (_Float16)ww[o * 1024 + j];
    } else if (j < 2048) {
        out = (_Float16)ww[o * 1024 + (j - 1024)];
    } else if (j < 3072) {
        const float v = ww[o * 1024 + (j - 2048)];
        const _Float16 hi = (_Float16)v;
        out = (_Float16)(v - (float)hi);
    } else {
        out = (g < 2) ? (_Float16)wu[o * 512 + (j - 3072)] : (_Float16)0.f;
    }
    Wbig[idx] = out;
}

__global__ void prep_m(const float* __restrict__ matrix,
                       _Float16* __restrict__ MTh, _Float16* __restrict__ MTl,
                       _Float16* __restrict__ Mrh, _Float16* __restrict__ Mrl)
{
    const int idx = blockIdx.x * 256 + threadIdx.x;   // KPAD*KPAD
    const int d = idx / KPAD, c = idx - d * KPAD;
    float vT = 0.f, vR = 0.f;
    if (d < C_ && c < C_) { vT = matrix[c * C_ + d]; vR = matrix[d * C_ + c]; }
    const _Float16 th = (_Float16)vT;
    const _Float16 rh = (_Float16)vR;
    MTh[idx] = th; MTl[idx] = (_Float16)(vT - (float)th);
    Mrh[idx] = rh; Mrl[idx] = (_Float16)(vR - (float)rh);
}

__global__ void prep_wout(const float* __restrict__ wout,
                          _Float16* __restrict__ WL, _Float16* __restrict__ WR)
{
    const int idx = blockIdx.x * 256 + threadIdx.x;   // 512*512
    const int o = idx >> 9, j = idx & 511;
    WL[idx] = (_Float16)wout[o * 1024 + j];
    WR[idx] = (_Float16)wout[o * 1024 + 512 + j];
}

// only the 151 real rows; rows 151..255 stay poisoned (never read downstream)
__global__ void prep_wcls(const float* __restrict__ wcls, _Float16* __restrict__ w16)
{
    const int k = blockIdx.x * 256 + threadIdx.x;   // 77312
    const int d = blockIdx.y;                        // 0..150
    w16[(size_t)d * (C_ * H_) + k] = (_Float16)wcls[(size_t)d * (C_ * H_) + k];
}

__global__ void k_cast(const float* __restrict__ src, _Float16* __restrict__ dst, int n)
{
    const int i = blockIdx.x * 256 + threadIdx.x;
    if (i < n) dst[i] = (_Float16)src[i];
}

__global__ void prep_bias(const float* b3w, const float* b3u, const float* b4w,
                          const float* b4u, const float* b5w, const float* b5u,
                          float* bz, float* br, float* b5)
{
    const int i = threadIdx.x;   // 512 threads
    bz[i] = b3w[i] + b3u[i];
    br[i] = b4w[i] + b4u[i];
    b5[i] = b5w[i] + b5u[i];
}

__global__ void prep_hid(const float* __restrict__ input, float* __restrict__ hid)
{
    const int idx = blockIdx.x * 256 + threadIdx.x;   // NR*128
    const unsigned row = idx >> 7;
    const int h4 = (idx & 127) << 2;
    const unsigned n = row / 151u;
    f32x4 v = *(const f32x4*)&input[(size_t)n * H_ + h4];
    *(f32x4*)&hid[(size_t)row * H_ + h4] = v;
}

__global__ void k_reduce(const float* __restrict__ partial, const float* __restrict__ bcls,
                         float* __restrict__ out)
{
    const int idx = blockIdx.x * 256 + threadIdx.x;   // NR
    const unsigned n = (unsigned)idx / 151u;
    const unsigned d = (unsigned)idx - n * 151u;
    float s = 0.f;
    for (int z = 0; z < C_; ++z)
        s += partial[(size_t)z * (NOBJ * 256) + n * 256 + d];
    out[idx] = s + bcls[d];
}

// ---------------------------------------------------------------------------

extern "C" void kernel_launch(void* const* d_in, const int* in_sizes, int n_in,
                              void* d_out, int out_size, void* d_ws, size_t ws_size,
                              hipStream_t stream)
{
    const float* input  = (const float*)d_in[0];
    const float* matrix = (const float*)d_in[1];
    const float* w3w = (const float*)d_in[2];
    const float* b3w = (const float*)d_in[3];
    const float* w3u = (const float*)d_in[4];
    const float* b3u = (const float*)d_in[5];
    const float* w4w = (const float*)d_in[6];
    const float* b4w = (const float*)d_in[7];
    const float* w4u = (const float*)d_in[8];
    const float* b4u = (const float*)d_in[9];
    const float* w5w = (const float*)d_in[10];
    const float* b5w = (const float*)d_in[11];
    const float* w5u = (const float*)d_in[12];
    const float* b5u = (const float*)d_in[13];
    const float* wout = (const float*)d_in[14];
    const float* bout = (const float*)d_in[15];
    const float* wcls = (const float*)d_in[16];
    const float* bcls = (const float*)d_in[17];
    float* obj = (float*)d_out;

    char* ws = (char*)d_ws;
    size_t off = 0;
    auto take = [&](size_t bytes) -> char* {
        off = (off + 255) & ~(size_t)255;
        char* p = ws + off;
        off += bytes;
        return p;
    };

    _Float16* Wbig  = (_Float16*)take((size_t)1536 * KV * 2);     // 11.01 MB
    _Float16* MTh   = (_Float16*)take((size_t)KPAD * KPAD * 2);
    _Float16* MTl   = (_Float16*)take((size_t)KPAD * KPAD * 2);
    _Float16* Mrh   = (_Float16*)take((size_t)KPAD * KPAD * 2);
    _Float16* Mrl   = (_Float16*)take((size_t)KPAD * KPAD * 2);
    _Float16* W5u16 = (_Float16*)take((size_t)512 * 512 * 2);
    _Float16* WL16  = (_Float16*)take((size_t)512 * 512 * 2);
    _Float16* WR16  = (_Float16*)take((size_t)512 * 512 * 2);
    _Float16* in16  = (_Float16*)take((size_t)256 * 512 * 2);
    float*    bz    = (float*)take(512 * 4);
    float*    br    = (float*)take(512 * 4);
    float*    b5    = (float*)take(512 * 4);
    float*    Stmp  = (float*)take((size_t)8 * C_ * H_ * 4);      //  2.47 MB
    float*    S32   = (float*)take((size_t)C_ * H_ * 4);
    float*    base  = (float*)take((size_t)256 * 512 * 4);
    float*    hid32 = (float*)take((size_t)NR * H_ * 4);          // 79.17 MB
    _Float16* AVH   = (_Float16*)take((size_t)CHP * KA * 2);      // 49.81 MB
    _Float16* prec  = (_Float16*)take((size_t)CHP * 1536 * 2);    // 29.88 MB
    // time-based aliases:
    _Float16* p5u = AVH;                 // 2 split-K halves: 2*CHP*512*2 = 19.9 MB < AVH
    _Float16* OUT16 = AVH;               // epilogue out (after loop)
    _Float16* Wcls16 = (_Float16*)hid32; // hid dead after epilogue GEMM
    float* partial = (float*)((char*)hid32 + (size_t)NOBJ * C_ * H_ * 2);

    (void)in_sizes; (void)n_in; (void)out_size; (void)ws_size;

    // ---- prep ----
    prep_wbig<<<dim3((1536 * KV) / 256), 256, 0, stream>>>(w3w, w3u, w4w, w4u, w5w, w5u, Wbig);
    prep_m<<<dim3((KPAD * KPAD) / 256), 256, 0, stream>>>(matrix, MTh, MTl, Mrh, Mrl);
    k_cast<<<dim3((512 * 512) / 256), 256, 0, stream>>>(w5u, W5u16, 512 * 512);
    prep_wout<<<dim3((512 * 512) / 256), 256, 0, stream>>>(wout, WL16, WR16);
    k_cast<<<dim3((256 * 512) / 256), 256, 0, stream>>>(input, in16, 256 * 512);
    prep_bias<<<dim3(1), 512, 0, stream>>>(b3w, b3u, b4w, b4u, b5w, b5u, bz, br, b5);
    prep_hid<<<dim3((NR * 128) / 256), 256, 0, stream>>>(input, hid32);
    gemm_kernel<0, _Float16, false><<<dim3(2, 4, 1), 256, 0, stream>>>(
        in16, 512, WR16, 512, base, 512, nullptr, nullptr, 512, 0);

    // ---- 3 GGNN steps, 4 object-chunks each ----
    for (int t = 0; t < 3; ++t) {
        k_sreduce<<<dim3(C_, 8), 64, 0, stream>>>(hid32, Stmp);
        k_sfold<<<dim3((C_ * H_) / 256), 256, 0, stream>>>(Stmp, S32);
        for (int cc = 0; cc < 4; ++cc) {
            const int cbase = cc * CH;
            mix_kernel<<<dim3(NCH, 8), 256, 0, stream>>>(
                hid32, S32, MTh, MTl, Mrh, Mrl, AVH, cbase);
            // gate GEMM (virtual K=3584), 128x256 tiles, 32x32x16 MFMA
            gemm_wide<1, true><<<dim3(CHP / 128, 1536 / 256, 1), 512, 0, stream>>>(
                AVH, KA, Wbig, KV, prec, 1536, KV, 0);
            k_ew1<<<dim3((CH * 128) / 256), 256, 0, stream>>>(prec, hid32, bz, br, cbase);
            // p5u = (r*h) @ W5u^T, split-K=2 (f16 partials summed in ew2)
            gemm_kernel<1, _Float16, false><<<dim3(CHP / 128, 4, 2), 256, 0, stream>>>(
                prec + 512, 1536, W5u16, 512, p5u, 512, nullptr, nullptr, 256, CHP * 512);
            k_ew2<<<dim3((CH * 128) / 256), 256, 0, stream>>>(
                prec, p5u, p5u + (size_t)CHP * 512, hid32, b5, cbase);
        }
    }

    // ---- epilogue: OUT = relu(hid @ WL^T + base[n] + bout)  (A is f32) ----
    gemm_kernel<2, float, false><<<dim3(NR / 128, 512 / 128, 1), 256, 0, stream>>>(
        hid32, 512, WL16, 512, OUT16, 512, bout, base, 512, 0);

    // ---- classifier: split-K over 151 chunks of 512 ----
    prep_wcls<<<dim3((C_ * H_) / 256, C_), 256, 0, stream>>>(wcls, Wcls16);
    gemm_kernel<0, _Float16, false><<<dim3(NOBJ / 128, 256 / 128, C_), 256, 0, stream>>>(
        OUT16, C_ * H_, Wcls16, C_ * H_, partial, 256, nullptr, nullptr, 512, NOBJ * 256);
    k_reduce<<<dim3(NR / 256), 256, 0, stream>>>(partial, bcls, obj);
}

// Round 10
// 2591.963 us; speedup vs baseline: 1.2397x; 1.1041x over previous
//
#include <hip/hip_runtime.h>

// ---------------------------------------------------------------------------
// GGNN-obj (N=256, C=151, H=512, T=3). Split-f16 (hi+lo) MFMA on the
// recurrent path, f32 hidden master.
// R9->R10: gate GEMM back to 16x16x32 (32x32 was -3% despite zero LDS
// conflicts -> barrier drain is the binding constraint, not LDS/MFMA).
// New: BK=64 staging via two 32-wide LDS buffer sets, ONE barrier pair per
// 64-k (halves barrier-drain count; occupancy unchanged at 48KB LDS).
// B dedup: physical Wbig = [Wh 1024 | Wl 1024 | Wu 512] (2560 cols), uniform
// kB remap (Wh read twice from same lines -> L2 hits). Bit-identical math.
// ---------------------------------------------------------------------------

#define C_     151
#define H_     512
#define NOBJ   256
#define NR     38656      // NOBJ * C_
#define NCH    64         // objects per chunk
#define CH     9664       // NCH * C_
#define CHP    9728       // CH padded to 128-multiple (76 tiles)
#define KPAD   160        // C_ padded to 32-multiple
#define KLDS   168        // LDS row stride for transposed x tiles
#define KA     2560       // A cols in gate GEMM: [av_hi 1024 | av_lo 1024 | h 512]
#define KV     3584       // virtual K: ah*Wh + al*Wh + ah*Wl + h*Wu
#define KB     2560       // physical B cols: [Wh 1024 | Wl 1024 | Wu 512]

typedef _Float16 half8 __attribute__((ext_vector_type(8)));
typedef _Float16 half4 __attribute__((ext_vector_type(4)));
typedef float    f32x4 __attribute__((ext_vector_type(4)));

__device__ __forceinline__ float sigm(float x) { return 1.f / (1.f + expf(-x)); }

__device__ __forceinline__ void gload16(const void* g, void* l) {
    __builtin_amdgcn_global_load_lds(
        (const __attribute__((address_space(1))) void*)g,
        (__attribute__((address_space(3))) void*)l, 16, 0, 0);
}

// Staging swizzle: LDS slot (row r, phys group p) holds logical k-group
// (p - r - (r>>2)) & 3; staging slot s fetches global k-offset kqswz(s).
__device__ __forceinline__ int kqswz(int s) {
    return 8 * (((s & 3) + 8 - ((s >> 2) & 3) - ((s >> 4) & 3)) & 3);
}
// 16x16 fragment read offset (row base multiple of 16):
__device__ __forceinline__ int fraswz(int lane) {
    const int lb = lane & 15;
    return lb * 32 + 8 * (((lane >> 4) + lb + (lb >> 2)) & 3);
}

__device__ __forceinline__ half8 loadA8(const _Float16* p) { return *(const half8*)p; }
__device__ __forceinline__ half8 loadA8(const float* p) {
    f32x4 a = *(const f32x4*)p;
    f32x4 b = *(const f32x4*)(p + 4);
    half8 o;
    #pragma unroll
    for (int j = 0; j < 4; ++j) { o[j] = (_Float16)a[j]; o[4 + j] = (_Float16)b[j]; }
    return o;
}

// ---------------------------------------------------------------------------
// 128x128-tile GEMM (256 thr, 16x16x32): Out[m,n] = sum_k A[m,k]*B[n,k].
// OP: 0 = f32 store, 1 = f16 store, 2 = relu(v+bias[col]+bias2[...]) -> f16
// ---------------------------------------------------------------------------
template<int OP, typename AT, bool DUPK>
__global__ __launch_bounds__(256, 2)
void gemm_kernel(const AT* __restrict__ A, int lda,
                 const _Float16* __restrict__ B, int ldb,
                 void* __restrict__ Out, int ldo,
                 const float* __restrict__ bias,
                 const float* __restrict__ bias2,
                 int kchunk, int chunkStride)
{
    constexpr bool A16 = (sizeof(AT) == 2);
    __shared__ _Float16 sA[128 * 32];
    __shared__ _Float16 sB[128 * 32];
    const int tid  = threadIdx.x;
    const int lane = tid & 63;
    const int w    = tid >> 6;
    const int m0   = blockIdx.x * 128;
    const int n0   = blockIdx.y * 128;
    const int kbase = blockIdx.z * kchunk;

    const int s0 = tid, s1 = tid + 256;
    const AT* Ap0 = A + (size_t)(m0 + (s0 >> 2)) * lda + kqswz(s0);
    const AT* Ap1 = A + (size_t)(m0 + (s1 >> 2)) * lda + kqswz(s1);
    const _Float16* Bp0 = B + (size_t)(n0 + (s0 >> 2)) * ldb + kbase + kqswz(s0);
    const _Float16* Bp1 = B + (size_t)(n0 + (s1 >> 2)) * ldb + kbase + kqswz(s1);
    const int la0 = 8 * s0;
    const int la1 = 8 * s1;
    _Float16* lA0 = &sA[w * 512];
    _Float16* lA1 = &sA[2048 + w * 512];
    _Float16* lB0 = &sB[w * 512];
    _Float16* lB1 = &sB[2048 + w * 512];

    f32x4 acc[4][4];
    #pragma unroll
    for (int i = 0; i < 4; ++i)
        #pragma unroll
        for (int j = 0; j < 4; ++j)
            #pragma unroll
            for (int r = 0; r < 4; ++r) acc[i][j][r] = 0.f;

    const int mrow = (w >> 1) * 64;
    const int ncol = (w & 1) * 64;
    const int fra  = fraswz(lane);

    for (int k0 = 0; k0 < kchunk; k0 += 32) {
        int kA;
        if (DUPK) kA = (k0 < 2048) ? k0 : ((k0 < 3072) ? k0 - 2048 : k0 - 1024);
        else      kA = kbase + k0;
        if constexpr (A16) {
            __syncthreads();
            gload16(Ap0 + kA, lA0);
            gload16(Ap1 + kA, lA1);
            gload16(Bp0 + k0, lB0);
            gload16(Bp1 + k0, lB1);
            __syncthreads();
        } else {
            half8 va0 = loadA8(Ap0 + kA);
            half8 va1 = loadA8(Ap1 + kA);
            half8 vb0 = *(const half8*)(Bp0 + k0);
            half8 vb1 = *(const half8*)(Bp1 + k0);
            __syncthreads();
            *(half8*)&sA[la0] = va0;
            *(half8*)&sA[la1] = va1;
            *(half8*)&sB[la0] = vb0;
            *(half8*)&sB[la1] = vb1;
            __syncthreads();
        }
        half8 af[4], bf[4];
        #pragma unroll
        for (int i = 0; i < 4; ++i)
            af[i] = *(const half8*)&sA[(mrow + i * 16) * 32 + fra];
        #pragma unroll
        for (int i = 0; i < 4; ++i)
            bf[i] = *(const half8*)&sB[(ncol + i * 16) * 32 + fra];
        #pragma unroll
        for (int mi = 0; mi < 4; ++mi)
            #pragma unroll
            for (int ni = 0; ni < 4; ++ni)
                acc[mi][ni] = __builtin_amdgcn_mfma_f32_16x16x32_f16(af[mi], bf[ni], acc[mi][ni], 0, 0, 0);
    }

    const size_t zoff = (size_t)blockIdx.z * (size_t)chunkStride;
    #pragma unroll
    for (int mi = 0; mi < 4; ++mi) {
        #pragma unroll
        for (int ni = 0; ni < 4; ++ni) {
            #pragma unroll
            for (int r = 0; r < 4; ++r) {
                const int row = m0 + mrow + mi * 16 + (lane >> 4) * 4 + r;
                const int col = n0 + ncol + ni * 16 + (lane & 15);
                float v = acc[mi][ni][r];
                const size_t o = zoff + (size_t)row * ldo + col;
                if (OP == 0) {
                    ((float*)Out)[o] = v;
                } else if (OP == 1) {
                    ((_Float16*)Out)[o] = (_Float16)v;
                } else {
                    const unsigned n = (unsigned)row / 151u;
                    v += bias[col] + bias2[n * 512u + col];
                    v = v > 0.f ? v : 0.f;
                    ((_Float16*)Out)[o] = (_Float16)v;
                }
            }
        }
    }
}

// ---------------------------------------------------------------------------
// 128(M)x256(N)-tile GEMM, 512 thr = 8 waves of 64x64, 16x16x32 MFMA.
// BK=64 staging: two independent 32-wide LDS buffer sets filled with ONE
// barrier pair, then two compute sub-steps -> half the barrier drains.
// DUPK: A virtual-K remap [ah|al|ah|h]; B remap kB=(k<1024?k:k-1024) over
// physical [Wh|Wl|Wu] (2560 cols).
// ---------------------------------------------------------------------------
template<int OP, bool DUPK>
__global__ __launch_bounds__(512, 2)
void gemm_wide(const _Float16* __restrict__ A, int lda,
               const _Float16* __restrict__ B, int ldb,
               void* __restrict__ Out, int ldo,
               int kchunk, int chunkStride)
{
    __shared__ _Float16 sA[2][128 * 32];   // 16 KB
    __shared__ _Float16 sB[2][256 * 32];   // 32 KB
    const int tid  = threadIdx.x;
    const int lane = tid & 63;
    const int w    = tid >> 6;              // 0..7
    const int m0   = blockIdx.x * 128;
    const int n0   = blockIdx.y * 256;
    const int kbase = blockIdx.z * kchunk;

    const int kq = kqswz(tid);
    const _Float16* Ap = A + (size_t)(m0 + (tid >> 2)) * lda + kq;
    const _Float16* Bp0 = B + (size_t)(n0 + (tid >> 2)) * ldb + kbase + kq;
    const _Float16* Bp1 = B + (size_t)(n0 + 128 + (tid >> 2)) * ldb + kbase + kq;
    _Float16* lA[2]  = { &sA[0][w * 512], &sA[1][w * 512] };
    _Float16* lB0[2] = { &sB[0][w * 512], &sB[1][w * 512] };
    _Float16* lB1[2] = { &sB[0][4096 + w * 512], &sB[1][4096 + w * 512] };

    f32x4 acc[4][4];
    #pragma unroll
    for (int i = 0; i < 4; ++i)
        #pragma unroll
        for (int j = 0; j < 4; ++j)
            #pragma unroll
            for (int r = 0; r < 4; ++r) acc[i][j][r] = 0.f;

    const int mrow = (w >> 2) * 64;          // 2 M-slices
    const int ncol = (w & 3) * 64;           // 4 N-slices
    const int fra  = fraswz(lane);

    for (int k0 = 0; k0 < kchunk; k0 += 64) {
        int kA[2], kB2[2];
        #pragma unroll
        for (int hf = 0; hf < 2; ++hf) {
            const int kk = k0 + 32 * hf;
            if (DUPK) {
                kA[hf]  = (kk < 2048) ? kk : ((kk < 3072) ? kk - 2048 : kk - 1024);
                kB2[hf] = (kk < 1024) ? kk : kk - 1024;
            } else {
                kA[hf]  = kbase + kk;
                kB2[hf] = kk;
            }
        }
        __syncthreads();
        #pragma unroll
        for (int hf = 0; hf < 2; ++hf) {
            gload16(Ap + kA[hf], lA[hf]);
            gload16(Bp0 + kB2[hf], lB0[hf]);
            gload16(Bp1 + kB2[hf], lB1[hf]);
        }
        __syncthreads();
        #pragma unroll
        for (int hf = 0; hf < 2; ++hf) {
            half8 af[4], bf[4];
            #pragma unroll
            for (int i = 0; i < 4; ++i)
                af[i] = *(const half8*)&sA[hf][(mrow + i * 16) * 32 + fra];
            #pragma unroll
            for (int i = 0; i < 4; ++i)
                bf[i] = *(const half8*)&sB[hf][(ncol + i * 16) * 32 + fra];
            #pragma unroll
            for (int mi = 0; mi < 4; ++mi)
                #pragma unroll
                for (int ni = 0; ni < 4; ++ni)
                    acc[mi][ni] = __builtin_amdgcn_mfma_f32_16x16x32_f16(af[mi], bf[ni], acc[mi][ni], 0, 0, 0);
        }
    }

    const size_t zoff = (size_t)blockIdx.z * (size_t)chunkStride;
    #pragma unroll
    for (int mi = 0; mi < 4; ++mi) {
        #pragma unroll
        for (int ni = 0; ni < 4; ++ni) {
            #pragma unroll
            for (int r = 0; r < 4; ++r) {
                const int row = m0 + mrow + mi * 16 + (lane >> 4) * 4 + r;
                const int col = n0 + ncol + ni * 16 + (lane & 15);
                const float v = acc[mi][ni][r];
                const size_t o = zoff + (size_t)row * ldo + col;
                if (OP == 0) ((float*)Out)[o] = v;
                else         ((_Float16*)Out)[o] = (_Float16)v;
            }
        }
    }
}

// ---------------------------------------------------------------------------
// Mix kernel (one 64-object chunk), split precision, xcast fused.
// ---------------------------------------------------------------------------
__global__ __launch_bounds__(256, 2)
void mix_kernel(const float* __restrict__ hid, const float* __restrict__ S,
                const _Float16* __restrict__ MTh, const _Float16* __restrict__ MTl,
                const _Float16* __restrict__ Mrh, const _Float16* __restrict__ Mrl,
                _Float16* __restrict__ AVH, int cbase)
{
    __shared__ _Float16 sxh[64 * KLDS];
    __shared__ _Float16 sxl[64 * KLDS];
    const int n  = blockIdx.x;
    const int h0 = blockIdx.y * 64;
    const int tid = threadIdx.x;

    #pragma unroll
    for (int i = 0; i < 5; ++i) {
        const int s  = tid + 256 * i;          // 0..1279
        const int c  = s >> 3;                 // 0..159
        const int hg = s & 7;
        half8 oh, ol;
        if (c < C_) {
            const float* hp = &hid[(size_t)(cbase + n * C_ + c) * H_ + h0 + hg * 8];
            const float* sp = &S[c * H_ + h0 + hg * 8];
            half8 hh;
            #pragma unroll
            for (int j = 0; j < 8; ++j) {
                const float hv = hp[j];
                const float x = sp[j] - hv;
                const _Float16 hi = (_Float16)x;
                oh[j] = hi;
                ol[j] = (_Float16)(x - (float)hi);
                hh[j] = (_Float16)hv;
            }
            *(half8*)&AVH[(size_t)(n * C_ + c) * KA + 2048 + h0 + hg * 8] = hh;
        } else {
            #pragma unroll
            for (int j = 0; j < 8; ++j) { oh[j] = (_Float16)0.f; ol[j] = (_Float16)0.f; }
        }
        #pragma unroll
        for (int j = 0; j < 8; ++j) {
            sxh[(hg * 8 + j) * KLDS + c] = oh[j];
            sxl[(hg * 8 + j) * KLDS + c] = ol[j];
        }
    }
    __syncthreads();

    const int lane = tid & 63;
    const int w    = tid >> 6;
    const _Float16* Mhi = (w >> 1) ? Mrh : MTh;
    const _Float16* Mlo = (w >> 1) ? Mrl : MTl;
    const int hb = (w & 1) * 32;

    f32x4 acc[10][2];
    #pragma unroll
    for (int i = 0; i < 10; ++i)
        #pragma unroll
        for (int j = 0; j < 2; ++j)
            #pragma unroll
            for (int r = 0; r < 4; ++r) acc[i][j][r] = 0.f;

    #pragma unroll
    for (int pass = 0; pass < 3; ++pass) {
        const _Float16* Ma = (pass == 2) ? Mlo : Mhi;
        const _Float16* X  = (pass == 1) ? sxl : sxh;
        #pragma unroll
        for (int kk = 0; kk < 5; ++kk) {
            const int k0 = kk * 32;
            half8 bf[2];
            #pragma unroll
            for (int ht = 0; ht < 2; ++ht)
                bf[ht] = *(const half8*)&X[(hb + ht * 16 + (lane & 15)) * KLDS + k0 + 8 * (lane >> 4)];
            #pragma unroll
            for (int dt = 0; dt < 10; ++dt) {
                half8 af = *(const half8*)&Ma[(dt * 16 + (lane & 15)) * KPAD + k0 + 8 * (lane >> 4)];
                acc[dt][0] = __builtin_amdgcn_mfma_f32_16x16x32_f16(af, bf[0], acc[dt][0], 0, 0, 0);
                acc[dt][1] = __builtin_amdgcn_mfma_f32_16x16x32_f16(af, bf[1], acc[dt][1], 0, 0, 0);
            }
        }
    }

    const int mixoff = (w >> 1) * 512;
    #pragma unroll
    for (int dt = 0; dt < 10; ++dt) {
        #pragma unroll
        for (int ht = 0; ht < 2; ++ht) {
            #pragma unroll
            for (int r = 0; r < 4; ++r) {
                const int d = dt * 16 + (lane >> 4) * 4 + r;
                if (d < C_) {
                    const int h = h0 + hb + ht * 16 + (lane & 15);
                    const float v = acc[dt][ht][r];
                    const _Float16 hi = (_Float16)v;
                    const _Float16 lo = (_Float16)(v - (float)hi);
                    _Float16* rowp = AVH + (size_t)(n * C_ + d) * KA + mixoff + h;
                    rowp[0]    = hi;
                    rowp[1024] = lo;
                }
            }
        }
    }
}

// --------------------------- small kernels ---------------------------------

__global__ void k_sreduce(const float* __restrict__ hid, float* __restrict__ Stmp)
{
    const int c  = blockIdx.x;      // 151
    const int g  = blockIdx.y;      // 8
    const int hw = threadIdx.x;     // 64
    const float* p = hid + (size_t)c * H_ + hw * 8;
    float s[8];
    #pragma unroll
    for (int j = 0; j < 8; ++j) s[j] = 0.f;
    const size_t stride = (size_t)C_ * H_;
    for (int n = g * 32; n < g * 32 + 32; ++n) {
        f32x4 a = *(const f32x4*)(p + (size_t)n * stride);
        f32x4 b = *(const f32x4*)(p + (size_t)n * stride + 4);
        #pragma unroll
        for (int j = 0; j < 4; ++j) { s[j] += a[j]; s[4 + j] += b[j]; }
    }
    float* o = Stmp + (size_t)g * (C_ * H_) + c * H_ + hw * 8;
    *(f32x4*)o       = f32x4{s[0], s[1], s[2], s[3]};
    *(f32x4*)(o + 4) = f32x4{s[4], s[5], s[6], s[7]};
}

__global__ void k_sfold(const float* __restrict__ Stmp, float* __restrict__ S)
{
    const int idx = blockIdx.x * 256 + threadIdx.x;   // 77312
    float s = 0.f;
    #pragma unroll
    for (int g = 0; g < 8; ++g) s += Stmp[(size_t)g * (C_ * H_) + idx];
    S[idx] = s;
}

__global__ void k_ew1(_Float16* __restrict__ pre, const float* __restrict__ hid,
                      const float* __restrict__ bz, const float* __restrict__ br, int cbase)
{
    const int idx = blockIdx.x * 256 + threadIdx.x;   // CH*128
    const unsigned r = idx >> 7;
    const int o4 = (idx & 127) << 2;
    const size_t base = (size_t)r * 1536;
    half4 zp = *(const half4*)&pre[base + o4];
    half4 rp = *(const half4*)&pre[base + 512 + o4];
    f32x4 hd = *(const f32x4*)&hid[(size_t)(cbase + r) * H_ + o4];
    f32x4 bz4 = *(const f32x4*)&bz[o4];
    f32x4 br4 = *(const f32x4*)&br[o4];
    half4 zs, rh;
    #pragma unroll
    for (int j = 0; j < 4; ++j) {
        float z = sigm((float)zp[j] + bz4[j]);
        float rr = sigm((float)rp[j] + br4[j]);
        zs[j] = (_Float16)z;
        rh[j] = (_Float16)(rr * hd[j]);
    }
    *(half4*)&pre[base + o4] = zs;
    *(half4*)&pre[base + 512 + o4] = rh;
}

// EW2: hv = tanh(pre_w5 + p5a + p5b + b5); h = (1-z)h + z*hv -> hid (f32)
__global__ void k_ew2(const _Float16* __restrict__ pre, const _Float16* __restrict__ p5a,
                      const _Float16* __restrict__ p5b,
                      float* __restrict__ hid, const float* __restrict__ b5, int cbase)
{
    const int idx = blockIdx.x * 256 + threadIdx.x;   // CH*128
    const unsigned r = idx >> 7;
    const int o4 = (idx & 127) << 2;
    const size_t base = (size_t)r * 1536;
    half4 w5 = *(const half4*)&pre[base + 1024 + o4];
    half4 pa = *(const half4*)&p5a[(size_t)r * H_ + o4];
    half4 pb = *(const half4*)&p5b[(size_t)r * H_ + o4];
    half4 zz = *(const half4*)&pre[base + o4];
    f32x4 hd = *(const f32x4*)&hid[(size_t)(cbase + r) * H_ + o4];
    f32x4 b54 = *(const f32x4*)&b5[o4];
    #pragma unroll
    for (int j = 0; j < 4; ++j) {
        float t = tanhf((float)w5[j] + (float)pa[j] + (float)pb[j] + b54[j]);
        float z = (float)zz[j];
        hd[j] = (1.f - z) * hd[j] + z * t;
    }
    *(f32x4*)&hid[(size_t)(cbase + r) * H_ + o4] = hd;
}

// --------------------------- prep kernels ----------------------------------

// Wbig [1536, 2560]: row op=(g*512+o): [0,1024)=Wg_hi; [1024,2048)=Wg_lo;
// [2048,2560)=Ug (0 for g=2).
__global__ void prep_wbig(const float* w3w, const float* w3u,
                          const float* w4w, const float* w4u,
                          const float* w5w, const float* w5u,
                          _Float16* __restrict__ Wbig)
{
    const int idx = blockIdx.x * 256 + threadIdx.x;   // 1536*2560
    const int op = idx / KB;
    const int j = idx - op * KB;
    const int g = op >> 9, o = op & 511;
    const float* ww = (g == 0) ? w3w : (g == 1) ? w4w : w5w;
    const float* wu = (g == 0) ? w3u : (g == 1) ? w4u : w5u;
    _Float16 out;
    if (j < 1024) {
        out = (_Float16)ww[o * 1024 + j];
    } else if (j < 2048) {
        const float v = ww[o * 1024 + (j - 1024)];
        const _Float16 hi = (_Float16)v;
        out = (_Float16)(v - (float)hi);
    } else {
        out = (g < 2) ? (_Float16)wu[o * 512 + (j - 2048)] : (_Float16)0.f;
    }
    Wbig[idx] = out;
}

__global__ void prep_m(const float* __restrict__ matrix,
                       _Float16* __restrict__ MTh, _Float16* __restrict__ MTl,
                       _Float16* __restrict__ Mrh, _Float16* __restrict__ Mrl)
{
    const int idx = blockIdx.x * 256 + threadIdx.x;   // KPAD*KPAD
    const int d = idx / KPAD, c = idx - d * KPAD;
    float vT = 0.f, vR = 0.f;
    if (d < C_ && c < C_) { vT = matrix[c * C_ + d]; vR = matrix[d * C_ + c]; }
    const _Float16 th = (_Float16)vT;
    const _Float16 rh = (_Float16)vR;
    MTh[idx] = th; MTl[idx] = (_Float16)(vT - (float)th);
    Mrh[idx] = rh; Mrl[idx] = (_Float16)(vR - (float)rh);
}

__global__ void prep_wout(const float* __restrict__ wout,
                          _Float16* __restrict__ WL, _Float16* __restrict__ WR)
{
    const int idx = blockIdx.x * 256 + threadIdx.x;   // 512*512
    const int o = idx >> 9, j = idx & 511;
    WL[idx] = (_Float16)wout[o * 1024 + j];
    WR[idx] = (_Float16)wout[o * 1024 + 512 + j];
}

// only the 151 real rows; rows 151..255 stay poisoned (never read downstream)
__global__ void prep_wcls(const float* __restrict__ wcls, _Float16* __restrict__ w16)
{
    const int k = blockIdx.x * 256 + threadIdx.x;   // 77312
    const int d = blockIdx.y;                        // 0..150
    w16[(size_t)d * (C_ * H_) + k] = (_Float16)wcls[(size_t)d * (C_ * H_) + k];
}

__global__ void k_cast(const float* __restrict__ src, _Float16* __restrict__ dst, int n)
{
    const int i = blockIdx.x * 256 + threadIdx.x;
    if (i < n) dst[i] = (_Float16)src[i];
}

__global__ void prep_bias(const float* b3w, const float* b3u, const float* b4w,
                          const float* b4u, const float* b5w, const float* b5u,
                          float* bz, float* br, float* b5)
{
    const int i = threadIdx.x;   // 512 threads
    bz[i] = b3w[i] + b3u[i];
    br[i] = b4w[i] + b4u[i];
    b5[i] = b5w[i] + b5u[i];
}

__global__ void prep_hid(const float* __restrict__ input, float* __restrict__ hid)
{
    const int idx = blockIdx.x * 256 + threadIdx.x;   // NR*128
    const unsigned row = idx >> 7;
    const int h4 = (idx & 127) << 2;
    const unsigned n = row / 151u;
    f32x4 v = *(const f32x4*)&input[(size_t)n * H_ + h4];
    *(f32x4*)&hid[(size_t)row * H_ + h4] = v;
}

__global__ void k_reduce(const float* __restrict__ partial, const float* __restrict__ bcls,
                         float* __restrict__ out)
{
    const int idx = blockIdx.x * 256 + threadIdx.x;   // NR
    const unsigned n = (unsigned)idx / 151u;
    const unsigned d = (unsigned)idx - n * 151u;
    float s = 0.f;
    for (int z = 0; z < C_; ++z)
        s += partial[(size_t)z * (NOBJ * 256) + n * 256 + d];
    out[idx] = s + bcls[d];
}

// ---------------------------------------------------------------------------

extern "C" void kernel_launch(void* const* d_in, const int* in_sizes, int n_in,
                              void* d_out, int out_size, void* d_ws, size_t ws_size,
                              hipStream_t stream)
{
    const float* input  = (const float*)d_in[0];
    const float* matrix = (const float*)d_in[1];
    const float* w3w = (const float*)d_in[2];
    const float* b3w = (const float*)d_in[3];
    const float* w3u = (const float*)d_in[4];
    const float* b3u = (const float*)d_in[5];
    const float* w4w = (const float*)d_in[6];
    const float* b4w = (const float*)d_in[7];
    const float* w4u = (const float*)d_in[8];
    const float* b4u = (const float*)d_in[9];
    const float* w5w = (const float*)d_in[10];
    const float* b5w = (const float*)d_in[11];
    const float* w5u = (const float*)d_in[12];
    const float* b5u = (const float*)d_in[13];
    const float* wout = (const float*)d_in[14];
    const float* bout = (const float*)d_in[15];
    const float* wcls = (const float*)d_in[16];
    const float* bcls = (const float*)d_in[17];
    float* obj = (float*)d_out;

    char* ws = (char*)d_ws;
    size_t off = 0;
    auto take = [&](size_t bytes) -> char* {
        off = (off + 255) & ~(size_t)255;
        char* p = ws + off;
        off += bytes;
        return p;
    };

    _Float16* Wbig  = (_Float16*)take((size_t)1536 * KB * 2);     //  7.86 MB
    _Float16* MTh   = (_Float16*)take((size_t)KPAD * KPAD * 2);
    _Float16* MTl   = (_Float16*)take((size_t)KPAD * KPAD * 2);
    _Float16* Mrh   = (_Float16*)take((size_t)KPAD * KPAD * 2);
    _Float16* Mrl   = (_Float16*)take((size_t)KPAD * KPAD * 2);
    _Float16* W5u16 = (_Float16*)take((size_t)512 * 512 * 2);
    _Float16* WL16  = (_Float16*)take((size_t)512 * 512 * 2);
    _Float16* WR16  = (_Float16*)take((size_t)512 * 512 * 2);
    _Float16* in16  = (_Float16*)take((size_t)256 * 512 * 2);
    float*    bz    = (float*)take(512 * 4);
    float*    br    = (float*)take(512 * 4);
    float*    b5    = (float*)take(512 * 4);
    float*    Stmp  = (float*)take((size_t)8 * C_ * H_ * 4);      //  2.47 MB
    float*    S32   = (float*)take((size_t)C_ * H_ * 4);
    float*    base  = (float*)take((size_t)256 * 512 * 4);
    float*    hid32 = (float*)take((size_t)NR * H_ * 4);          // 79.17 MB
    _Float16* AVH   = (_Float16*)take((size_t)CHP * KA * 2);      // 49.81 MB
    _Float16* prec  = (_Float16*)take((size_t)CHP * 1536 * 2);    // 29.88 MB
    // time-based aliases:
    _Float16* p5u = AVH;                 // 2 split-K halves: 2*CHP*512*2 = 19.9 MB < AVH
    _Float16* OUT16 = AVH;               // epilogue out (after loop)
    _Float16* Wcls16 = (_Float16*)hid32; // hid dead after epilogue GEMM
    float* partial = (float*)((char*)hid32 + (size_t)NOBJ * C_ * H_ * 2);

    (void)in_sizes; (void)n_in; (void)out_size; (void)ws_size;

    // ---- prep ----
    prep_wbig<<<dim3((1536 * KB) / 256), 256, 0, stream>>>(w3w, w3u, w4w, w4u, w5w, w5u, Wbig);
    prep_m<<<dim3((KPAD * KPAD) / 256), 256, 0, stream>>>(matrix, MTh, MTl, Mrh, Mrl);
    k_cast<<<dim3((512 * 512) / 256), 256, 0, stream>>>(w5u, W5u16, 512 * 512);
    prep_wout<<<dim3((512 * 512) / 256), 256, 0, stream>>>(wout, WL16, WR16);
    k_cast<<<dim3((256 * 512) / 256), 256, 0, stream>>>(input, in16, 256 * 512);
    prep_bias<<<dim3(1), 512, 0, stream>>>(b3w, b3u, b4w, b4u, b5w, b5u, bz, br, b5);
    prep_hid<<<dim3((NR * 128) / 256), 256, 0, stream>>>(input, hid32);
    gemm_kernel<0, _Float16, false><<<dim3(2, 4, 1), 256, 0, stream>>>(
        in16, 512, WR16, 512, base, 512, nullptr, nullptr, 512, 0);

    // ---- 3 GGNN steps, 4 object-chunks each ----
    for (int t = 0; t < 3; ++t) {
        k_sreduce<<<dim3(C_, 8), 64, 0, stream>>>(hid32, Stmp);
        k_sfold<<<dim3((C_ * H_) / 256), 256, 0, stream>>>(Stmp, S32);
        for (int cc = 0; cc < 4; ++cc) {
            const int cbase = cc * CH;
            mix_kernel<<<dim3(NCH, 8), 256, 0, stream>>>(
                hid32, S32, MTh, MTl, Mrh, Mrl, AVH, cbase);
            // gate GEMM (virtual K=3584 over physical B 2560), 128x256, BK=64
            gemm_wide<1, true><<<dim3(CHP / 128, 1536 / 256, 1), 512, 0, stream>>>(
                AVH, KA, Wbig, KB, prec, 1536, KV, 0);
            k_ew1<<<dim3((CH * 128) / 256), 256, 0, stream>>>(prec, hid32, bz, br, cbase);
            // p5u = (r*h) @ W5u^T, split-K=2 (f16 partials summed in ew2)
            gemm_kernel<1, _Float16, false><<<dim3(CHP / 128, 4, 2), 256, 0, stream>>>(
                prec + 512, 1536, W5u16, 512, p5u, 512, nullptr, nullptr, 256, CHP * 512);
            k_ew2<<<dim3((CH * 128) / 256), 256, 0, stream>>>(
                prec, p5u, p5u + (size_t)CHP * 512, hid32, b5, cbase);
        }
    }

    // ---- epilogue: OUT = relu(hid @ WL^T + base[n] + bout)  (A is f32) ----
    gemm_kernel<2, float, false><<<dim3(NR / 128, 512 / 128, 1), 256, 0, stream>>>(
        hid32, 512, WL16, 512, OUT16, 512, bout, base, 512, 0);

    // ---- classifier: split-K over 151 chunks of 512 ----
    prep_wcls<<<dim3((C_ * H_) / 256, C_), 256, 0, stream>>>(wcls, Wcls16);
    gemm_kernel<0, _Float16, false><<<dim3(NOBJ / 128, 256 / 128, C_), 256, 0, stream>>>(
        OUT16, C_ * H_, Wcls16, C_ * H_, partial, 256, nullptr, nullptr, 512, NOBJ * 256);
    k_reduce<<<dim3(NR / 256), 256, 0, stream>>>(partial, bcls, obj);
}